// Round 3
// baseline (124.466 us; speedup 1.0000x reference)
//
#include <hip/hip_runtime.h>
#include <hip/hip_bf16.h>
#include <math.h>

// CapsNet dynamic routing. R19 = register-resident uhat rewrite.
// R18 post-mortem: routing is LDS-pipe + lockstep-latency bound (~67 ds-ops/
// wave/round) with a 20% grid tail (1280 blocks / 512 resident = 2.5 gens);
// cutting VALU did nothing. R19 restructure:
//  - block = 512 thr (8 waves); wave w owns i-rows {64w+l, 512+64w+l,
//    1024+16w+l(l<16)} for BOTH batches -> W read once per block (no 2x).
//  - uhat f16 pairs in REGISTERS (<=48 VGPR/lane); L-logits in regs; ce gone.
//  - s-partials accumulated in-register (v_pk_fma_f16) inside the b-update;
//    NO separate s-pass; cross-lane reduce via narrowing XOR tree (10 shfl).
//  - f16 c=exp(L-M_w) with per-wave max M_w; combine rescales by expf(M_w)
//    (exact math; same f32 range envelope as the max-free exp, R6-R18).
//  - LDS = 1.7 KB (spart 288 dw + vbuf 128 dw); 3 syncthreads total.
//  - grid 1280 x 512, 1 block/CU -> exactly 5 generations, ZERO tail.
// Tripwires: VGPR <= 128 (no spill; WRITE_SIZE ~160 KB), absmax < 0.0078.
// W pre-pass layout [g=i/64][j][k=m][lg=i%64][kn] f16 n-pairs -> lane-coalesced.
//
// u: [256][1152][8] f32; weight: [1152][10][8][16] f32; out: [256][10][16] f32

#define IC 1152
#define OC 10
#define NB 256

#define NW_DW (18 * OC * 16 * 256)    // 737280 dwords: W f16 pairs, new layout
#define NU_DW (NB * IC * 4)           // 1179648 dwords: u as f16 n-pairs
#define WS_NEED ((size_t)(NW_DW + NU_DW) * 4)

typedef float v2f __attribute__((ext_vector_type(2)));
typedef _Float16 h2 __attribute__((ext_vector_type(2)));

#if defined(__has_builtin)
#if __has_builtin(__builtin_amdgcn_fdot2)
#define HAVE_FDOT2 1
#endif
#endif

__device__ __forceinline__ float fdot2f(unsigned w, unsigned uu, float c) {
    h2 a = *(h2*)&w, b = *(h2*)&uu;
#ifdef HAVE_FDOT2
    return __builtin_amdgcn_fdot2(a, b, c, false);
#else
    return c + (float)a.x * (float)b.x + (float)a.y * (float)b.y;
#endif
}
__device__ __forceinline__ v2f h_v2(unsigned w) {
    h2 h = *(h2*)&w;
    v2f r = {(float)h.x, (float)h.y};
    return r;
}
__device__ __forceinline__ unsigned packh2(float a, float b) {
    h2 h = {(_Float16)a, (_Float16)b};
    return *(unsigned*)&h;
}
__device__ __forceinline__ unsigned h2u(h2 v) { return *(unsigned*)&v; }
__device__ __forceinline__ h2 u2h(unsigned v) { return *(h2*)&v; }
__device__ __forceinline__ h2 hshfl_xor(h2 v, int m) {
    unsigned b = *(unsigned*)&v;
    unsigned r = (unsigned)__shfl_xor((int)b, m, 64);
    return *(h2*)&r;
}

// ---- Pre-pass: W f32 -> f16 n-pairs, [g][j][m=k][lg][kn]; u f32 -> f16 pairs ----
__global__ void convert_kernel(const float* __restrict__ u,
                               const float* __restrict__ W,
                               unsigned* __restrict__ ws, int do_u) {
    const int tid = blockIdx.x * blockDim.x + threadIdx.x;
    if (tid < NW_DW) {
        const int kn = tid & 3, lg = (tid >> 2) & 63, k = (tid >> 8) & 15;
        const int rest = tid >> 12, j = rest % OC, g = rest / OC;
        const int i = (g << 6) + lg;
        const float* s = W + (((size_t)(i * OC + j)) << 7) + (kn << 5) + k;
        ws[tid] = packh2(s[0], s[16]);
    } else if (do_u) {
        const int e = tid - NW_DW;
        if (e < NU_DW) {
            const int pr = e & 3, bi = e >> 2;
            const float* s = u + ((size_t)bi << 3) + (pr << 1);
            ws[NW_DW + e] = packh2(s[0], s[1]);
        }
    }
}

template<bool UF16>
__global__ __launch_bounds__(512, 2)
void caps_route_kernel(const float* __restrict__ u,
                       const unsigned* __restrict__ Wh,
                       const unsigned* __restrict__ ug,
                       float* __restrict__ out) {
    // spart per parity pi: [0..7]=Mpk  [8..15]=sepk  [16 + bt*64 + p*8 + w]
    __shared__ unsigned spart[2 * 144];
    __shared__ unsigned vbuf[8 * 16];   // [wave][bt*8+p] packed v f16 pairs

    const int t    = threadIdx.x;
    const int bx   = blockIdx.x;
    const int lane = t & 63;
    const int wid  = t >> 6;            // 0..7

    // XCD-aware (j, batch-pair) mapping (xcd = bx & 7 heuristic).
    int x = bx & 7, sg = bx >> 3;
    int j, p;
    if (sg < 128) { j = x; p = sg; }
    else { int s2v = sg - 128; j = 8 + (x >> 2); p = ((x & 3) << 5) + s2v; }
    const int bb = p * 2;  // batches bb, bb+1

    // ---- own rows: g1=wid, g2=8+wid, g3=16+(wid>>2) (lanes 0-15) ----
    const int g3  = 16 + (wid >> 2);
    const int lg3 = ((wid & 3) << 4) + lane;   // valid only lane<16
    const int i1  = (wid << 6) + lane;
    const int i2  = 512 + i1;
    const int i3  = (g3 << 6) + lg3;

    unsigned uhA[3][8], uhB[3][8];   // per-row f16 m-pairs (p -> m 2p,2p+1)

    auto rowcalc = [&](int g, int lgv, uint4 Ua, uint4 Ub, unsigned* rA, unsigned* rB) {
        const uint4* wp = (const uint4*)Wh + (size_t)(g * OC + j) * 1024 + lgv;
#pragma unroll
        for (int pp = 0; pp < 8; ++pp) {
            const uint4 w0 = wp[(2 * pp) * 64];
            const uint4 w1 = wp[(2 * pp + 1) * 64];
            float A0 = fdot2f(w0.x, Ua.x, 0.f); A0 = fdot2f(w0.y, Ua.y, A0);
            A0 = fdot2f(w0.z, Ua.z, A0);        A0 = fdot2f(w0.w, Ua.w, A0);
            float A1 = fdot2f(w1.x, Ua.x, 0.f); A1 = fdot2f(w1.y, Ua.y, A1);
            A1 = fdot2f(w1.z, Ua.z, A1);        A1 = fdot2f(w1.w, Ua.w, A1);
            float B0 = fdot2f(w0.x, Ub.x, 0.f); B0 = fdot2f(w0.y, Ub.y, B0);
            B0 = fdot2f(w0.z, Ub.z, B0);        B0 = fdot2f(w0.w, Ub.w, B0);
            float B1 = fdot2f(w1.x, Ub.x, 0.f); B1 = fdot2f(w1.y, Ub.y, B1);
            B1 = fdot2f(w1.z, Ub.z, B1);        B1 = fdot2f(w1.w, Ub.w, B1);
            rA[pp] = packh2(A0, A1);
            rB[pp] = packh2(B0, B1);
        }
    };

    auto fetchU = [&](int i, uint4& Ua, uint4& Ub) {
        if constexpr (UF16) {
            const uint4* ua4 = (const uint4*)ug + (size_t)bb * IC;
            Ua = ua4[i];
            Ub = ua4[IC + i];
        } else {
            const float* u0p = u + (size_t)bb * (IC * 8);
            const float4 a0 = *(const float4*)(u0p + i * 8);
            const float4 a1 = *(const float4*)(u0p + i * 8 + 4);
            const float4 b0 = *(const float4*)(u0p + IC * 8 + i * 8);
            const float4 b1 = *(const float4*)(u0p + IC * 8 + i * 8 + 4);
            Ua = make_uint4(packh2(a0.x, a0.y), packh2(a0.z, a0.w),
                            packh2(a1.x, a1.y), packh2(a1.z, a1.w));
            Ub = make_uint4(packh2(b0.x, b0.y), packh2(b0.z, b0.w),
                            packh2(b1.x, b1.y), packh2(b1.z, b1.w));
        }
    };

    // narrowing XOR tree: in: 8 h2 partials/lane (all-m); out: one h2 per lane,
    // full 64-lane sum for m-pair p=(lane>>3)&7 (replicated over lane&7).
    auto tree8 = [&](h2* s) -> h2 {
        const bool b5 = (lane & 32) != 0, b4 = (lane & 16) != 0, b3 = (lane & 8) != 0;
        h2 tq[4];
#pragma unroll
        for (int q = 0; q < 4; ++q) {
            h2 snd = b5 ? s[q] : s[q + 4];
            tq[q] = (b5 ? s[q + 4] : s[q]) + hshfl_xor(snd, 32);
        }
        h2 uq[2];
#pragma unroll
        for (int q = 0; q < 2; ++q) {
            h2 snd = b4 ? tq[q] : tq[q + 2];
            uq[q] = (b4 ? tq[q + 2] : tq[q]) + hshfl_xor(snd, 16);
        }
        h2 xq;
        {
            h2 snd = b3 ? uq[0] : uq[1];
            xq = (b3 ? uq[1] : uq[0]) + hshfl_xor(snd, 8);
        }
        xq += hshfl_xor(xq, 4);
        xq += hshfl_xor(xq, 2);
        xq += hshfl_xor(xq, 1);
        return xq;
    };

    const int sel = lane & 7;

    // ---- Phase A: uhat rows -> registers; r0 partials (c=1) ----
    {
        uint4 Ua, Ub;
        fetchU(i1, Ua, Ub);
        rowcalc(wid, lane, Ua, Ub, uhA[0], uhB[0]);
        fetchU(i2, Ua, Ub);
        rowcalc(8 + wid, lane, Ua, Ub, uhA[1], uhB[1]);
        if (lane < 16) {
            fetchU(i3, Ua, Ub);
            rowcalc(g3, lg3, Ua, Ub, uhA[2], uhB[2]);
        } else {
#pragma unroll
            for (int pp = 0; pp < 8; ++pp) { uhA[2][pp] = 0u; uhB[2][pp] = 0u; }
        }
        h2 sa[8], sb[8];
#pragma unroll
        for (int pp = 0; pp < 8; ++pp) {
            sa[pp] = u2h(uhA[0][pp]) + u2h(uhA[1][pp]) + u2h(uhA[2][pp]);
            sb[pp] = u2h(uhB[0][pp]) + u2h(uhB[1][pp]) + u2h(uhB[2][pp]);
        }
        h2 ta = tree8(sa), tb = tree8(sb);
        if (sel < 2)
            spart[16 + sel * 64 + (lane >> 3) * 8 + wid] = sel ? h2u(tb) : h2u(ta);
        else if (sel == 2) spart[wid] = packh2(0.f, 0.f);        // M = 0
        else if (sel == 3) spart[8 + wid] = packh2(144.f, 144.f); // se = rows/wave/bt
    }

    __syncthreads();  // B0

    float LA[3], LB[3];
    LA[0] = 0.f; LA[1] = 0.f; LA[2] = (lane < 16) ? 0.f : -1e30f;
    LB[0] = 0.f; LB[1] = 0.f; LB[2] = (lane < 16) ? 0.f : -1e30f;

    const int cp = lane & 7, cbt = (lane >> 3) & 1;

    for (int r = 0; r < 3; ++r) {
        const int pi = (r & 1) * 144;
        // ---- combine: s = sum_w e^{M_w} partial_w ; squash -> v ----
        const uint4 q0 = *(const uint4*)&spart[pi + 16 + cbt * 64 + cp * 8];
        const uint4 q1 = *(const uint4*)&spart[pi + 16 + cbt * 64 + cp * 8 + 4];
        const uint4 m0 = *(const uint4*)&spart[pi];
        const uint4 m1 = *(const uint4*)&spart[pi + 4];
        const uint4 e0 = *(const uint4*)&spart[pi + 8];
        const uint4 e1 = *(const uint4*)&spart[pi + 12];
        v2f s2 = {0.f, 0.f};
        float ses = 0.f;
#define CW(qc, mc, ec) {                                                  \
        const h2 mh = u2h(mc); const h2 eh = u2h(ec);                     \
        const float fac = __expf((float)(cbt ? mh.y : mh.x));             \
        const v2f pv = h_v2(qc);                                          \
        s2.x += pv.x * fac; s2.y += pv.y * fac;                           \
        ses += (float)(cbt ? eh.y : eh.x) * fac; }
        CW(q0.x, m0.x, e0.x) CW(q0.y, m0.y, e0.y)
        CW(q0.z, m0.z, e0.z) CW(q0.w, m0.w, e0.w)
        CW(q1.x, m1.x, e1.x) CW(q1.y, m1.y, e1.y)
        CW(q1.z, m1.z, e1.z) CW(q1.w, m1.w, e1.w)
#undef CW
        const float inv = 1.0f / ses;
        const float sx = s2.x * inv, sy = s2.y * inv;
        float p2 = sx * sx + sy * sy;
        p2 += __shfl_xor(p2, 1, 64);
        p2 += __shfl_xor(p2, 2, 64);
        p2 += __shfl_xor(p2, 4, 64);
        const float sc = p2 / ((1.0f + p2) * sqrtf(p2 + 1e-8f));
        const float vx = sx * sc, vy = sy * sc;

        if (r == 2) {
            if (lane < 16)
                *(float2*)&out[((size_t)(bb + cbt) * OC + j) * 16 + (cp << 1)] =
                    make_float2(vx, vy);
            break;
        }

        if (lane < 16) vbuf[(wid << 4) + lane] = packh2(vx, vy);
        asm volatile("s_waitcnt lgkmcnt(0)" ::: "memory");

        // ---- b-update + fused next-round s-partials (all in registers) ----
        const uint4 va0 = *(const uint4*)&vbuf[(wid << 4)];
        const uint4 va1 = *(const uint4*)&vbuf[(wid << 4) + 4];
        const uint4 vb0 = *(const uint4*)&vbuf[(wid << 4) + 8];
        const uint4 vb1 = *(const uint4*)&vbuf[(wid << 4) + 12];
#define DP8(Lk, U, A0, A1) { float d = fdot2f((U)[0], (A0).x, 0.f);       \
        d = fdot2f((U)[1], (A0).y, d); d = fdot2f((U)[2], (A0).z, d);     \
        d = fdot2f((U)[3], (A0).w, d); d = fdot2f((U)[4], (A1).x, d);     \
        d = fdot2f((U)[5], (A1).y, d); d = fdot2f((U)[6], (A1).z, d);     \
        d = fdot2f((U)[7], (A1).w, d); (Lk) += d; }
        DP8(LA[0], uhA[0], va0, va1)
        DP8(LA[1], uhA[1], va0, va1)
        DP8(LA[2], uhA[2], va0, va1)
        DP8(LB[0], uhB[0], vb0, vb1)
        DP8(LB[1], uhB[1], vb0, vb1)
        DP8(LB[2], uhB[2], vb0, vb1)
#undef DP8
        // per-wave max (f32 chains), stored/used as f16-rounded (consistent)
        float MA = fmaxf(LA[0], fmaxf(LA[1], LA[2]));
        float MB = fmaxf(LB[0], fmaxf(LB[1], LB[2]));
#pragma unroll
        for (int o = 32; o >= 1; o >>= 1) {
            MA = fmaxf(MA, __shfl_xor(MA, o, 64));
            MB = fmaxf(MB, __shfl_xor(MB, o, 64));
        }
        const unsigned mdw = packh2(MA, MB);
        const h2 mh2 = u2h(mdw);
        const float MAu = (float)mh2.x, MBu = (float)mh2.y;

        h2 sa[8], sb[8];
#pragma unroll
        for (int pp = 0; pp < 8; ++pp) { sa[pp] = (h2){0.f, 0.f}; sb[pp] = (h2){0.f, 0.f}; }
        float seA = 0.f, seB = 0.f;
#pragma unroll
        for (int r3 = 0; r3 < 3; ++r3) {
            const float evA = __expf(LA[r3] - MAu);
            const float evB = __expf(LB[r3] - MBu);
            seA += evA; seB += evB;
            const h2 ca = u2h(packh2(evA, evA));
            const h2 cb = u2h(packh2(evB, evB));
#pragma unroll
            for (int pp = 0; pp < 8; ++pp) {
                sa[pp] += u2h(uhA[r3][pp]) * ca;   // v_pk_fma_f16
                sb[pp] += u2h(uhB[r3][pp]) * cb;
            }
        }
        h2 seh = u2h(packh2(seA, seB));
#pragma unroll
        for (int o = 32; o >= 1; o >>= 1) seh += hshfl_xor(seh, o);

        const h2 ta = tree8(sa), tb = tree8(sb);
        const int po = ((r + 1) & 1) * 144;
        if (sel < 2)
            spart[po + 16 + sel * 64 + (lane >> 3) * 8 + wid] = sel ? h2u(tb) : h2u(ta);
        else if (sel == 2) spart[po + wid] = mdw;
        else if (sel == 3) spart[po + 8 + wid] = h2u(seh);
        __syncthreads();  // B(r+1)
    }
}

extern "C" void kernel_launch(void* const* d_in, const int* in_sizes, int n_in,
                              void* d_out, int out_size, void* d_ws, size_t ws_size,
                              hipStream_t stream) {
    const float* u = (const float*)d_in[0];
    const float* W = (const float*)d_in[1];
    float* out = (float*)d_out;
    unsigned* ws = (unsigned*)d_ws;

    const int do_u = (ws_size >= WS_NEED) ? 1 : 0;
    const int total = NW_DW + (do_u ? NU_DW : 0);
    convert_kernel<<<(total + 255) / 256, 256, 0, stream>>>(u, W, ws, do_u);

    if (do_u)
        caps_route_kernel<true><<<(NB / 2) * OC, 512, 0, stream>>>(u, ws, ws + NW_DW, out);
    else
        caps_route_kernel<false><<<(NB / 2) * OC, 512, 0, stream>>>(u, ws, ws + NW_DW, out);
}

// Round 4
// 108.740 us; speedup vs baseline: 1.1446x; 1.1446x over previous
//
#include <hip/hip_runtime.h>
#include <hip/hip_bf16.h>
#include <math.h>

// CapsNet dynamic routing. R20 = R17 geometry + fused update/s-pass rounds.
// R19 post-mortem: occupancy is king (R17 72%->51.5us; R19 20%->57.4us);
// latency-bound, not work-bound. R20 keeps R17's 1024-thr / 2-blocks-per-CU
// / 32-VGPR shape and cuts the ROUND STRUCTURE:
//  - fuse b-update + next s-pass: per row, pass1 dp->L; wave-max M; pass2
//    re-read row, ev=exp(L-M), s-partials in-register via v_pk_fma_f16.
//  - ce array GONE (-4.6KB LDS), s-pass cvt loop GONE, 4 -> 3 barriers.
//  - s-partial reduce: narrowing XOR tree (10 shfl); m-space/position-space
//    (half-XOR uhat swizzle) reconciled for FREE: tree step1 selects on
//    (lane5 ^ eB); v-broadcast gathers via bpermute index (k ^ eB*4).
//  - combine: s = sum_w exp(M_w)*part_w / sum_w exp(M_w)*se_w (exact
//    softmax; exp(M_w) f32-safe since raw exp(L) was f32-safe R6-R18).
//  - r0 uses R18's Phase-A-fused column sums (c uniform), proven absmax-ok.
// Tripwires: VGPR == 32 (2-block residency), WRITE_SIZE ~160KB (spill),
// occupancy ~70%, absmax < 0.0078.
//
// u: [256][1152][8] f32; weight: [1152][10][8][16] f32; out: [256][10][16] f32

#define IC 1152
#define OC 10
#define NB 256
#define TILE_DW (IC * 8)              // dwords per batch tile (f16-packed)

#define NW_DW (IC * OC * 64)          // 737280 dwords: W as f16 n-pairs
#define NU_DW (NB * IC * 4)           // 1179648 dwords: u as f16 n-pairs
#define WS_NEED ((size_t)(NW_DW + NU_DW) * 4)

typedef float v2f __attribute__((ext_vector_type(2)));
typedef _Float16 h2 __attribute__((ext_vector_type(2)));

#if defined(__has_builtin)
#if __has_builtin(__builtin_amdgcn_fdot2)
#define HAVE_FDOT2 1
#endif
#endif

__device__ __forceinline__ float fdot2f(unsigned w, unsigned uu, float c) {
    h2 a = *(h2*)&w, b = *(h2*)&uu;
#ifdef HAVE_FDOT2
    return __builtin_amdgcn_fdot2(a, b, c, false);
#else
    return c + (float)a.x * (float)b.x + (float)a.y * (float)b.y;
#endif
}
__device__ __forceinline__ v2f h_v2(unsigned w) {
    h2 h = *(h2*)&w;
    v2f r = {(float)h.x, (float)h.y};
    return r;
}
__device__ __forceinline__ unsigned packh2(float a, float b) {
    h2 h = {(_Float16)a, (_Float16)b};
    return *(unsigned*)&h;
}
__device__ __forceinline__ unsigned h2u(h2 v) { return *(unsigned*)&v; }
__device__ __forceinline__ h2 u2h(unsigned v) { return *(h2*)&v; }
__device__ __forceinline__ h2 hshfl_xor(h2 v, int m) {
    unsigned b = *(unsigned*)&v;
    unsigned r = (unsigned)__shfl_xor((int)b, m, 64);
    return *(h2*)&r;
}

// ---- Pre-pass: W f32 -> f16 pairs along n, transposed; u f32 -> f16 pairs ----
// Wh dword e: kn=e&3 (n-pair), mp=(e>>2)&3, q=(e>>4)&3, ij=e>>6; m=q*4+mp
__global__ void convert_kernel(const float* __restrict__ u,
                               const float* __restrict__ W,
                               unsigned* __restrict__ ws, int do_u) {
    const int tid = blockIdx.x * blockDim.x + threadIdx.x;
    if (tid < NW_DW) {
        const int k = tid & 3, mp = (tid >> 2) & 3, q = (tid >> 4) & 3, ij = tid >> 6;
        const int m = (q << 2) + mp;
        const float* s = W + ((size_t)ij << 7) + m + (k << 5);
        ws[tid] = packh2(s[0], s[16]);
    } else if (do_u) {
        const int e = tid - NW_DW;
        if (e < NU_DW) {
            const int pr = e & 3, bi = e >> 2;
            const float* s = u + ((size_t)bi << 3) + (pr << 1);
            ws[NW_DW + e] = packh2(s[0], s[1]);
        }
    }
}

template<bool UF16>
__global__ __launch_bounds__(1024, 8)
void caps_route_kernel(const float* __restrict__ u,
                       const unsigned* __restrict__ Wh,
                       const unsigned* __restrict__ ug,
                       float* __restrict__ out) {
    extern __shared__ unsigned smem_u[];
    unsigned* uh   = smem_u;                 // 2 tiles (73728 B)
    unsigned* r0p  = uh + 2 * TILE_DW;       // [2 bt][16 wid][8 dw] f16 (1024 B)
    unsigned* spart = r0p + 256;             // [2 par][part 128 | Mse 32] (1280 B)

    const int t    = threadIdx.x;
    const int bx   = blockIdx.x;
    const int lane = t & 63;
    const int wid  = t >> 6;

    // XCD-aware (j, batch-pair) mapping (xcd = bx & 7 heuristic).
    int x = bx & 7, sg = bx >> 3;
    int j, p;
    if (sg < 128) { j = x; p = sg; }
    else { int s2v = sg - 128; j = 8 + (x >> 2); p = ((x & 3) << 5) + s2v; }
    const int bb = p * 2;  // batches bb, bb+1

    // ---- Phase A: uhat -> LDS f16 (half-XOR swizzle) + r0 column sums ----
    // (R18-proven structure; pairwise W loads keep the 32-VGPR wall.)
    {
        const int q  = t & 3;
        const int i0 = t >> 2;           // 0..255
        const int pb = (((q >> 1) ^ ((i0 >> 2) & 1)) << 2) + ((q & 1) << 1);
        const float* u0p = u + (size_t)bb * (IC * 8);
        const uint4* ua4 = (const uint4*)ug + (size_t)bb * IC;
        const uint4* ub4 = ua4 + IC;

        h2 sA01 = u2h(0u), sA23 = u2h(0u);
        h2 sB01 = u2h(0u), sB23 = u2h(0u);

        auto stage = [&](int i) {
            const uint4* wq4 = (const uint4*)Wh + (((size_t)(i * OC + j) << 2) + q) * 4;
            uint4 Ua, Ub;
            if constexpr (UF16) {
                Ua = ua4[i];
                Ub = ub4[i];
            } else {
                const float4 a0 = *(const float4*)(u0p + i * 8);
                const float4 a1 = *(const float4*)(u0p + i * 8 + 4);
                const float4 b0 = *(const float4*)(u0p + IC * 8 + i * 8);
                const float4 b1 = *(const float4*)(u0p + IC * 8 + i * 8 + 4);
                Ua = make_uint4(packh2(a0.x, a0.y), packh2(a0.z, a0.w),
                                packh2(a1.x, a1.y), packh2(a1.z, a1.w));
                Ub = make_uint4(packh2(b0.x, b0.y), packh2(b0.z, b0.w),
                                packh2(b1.x, b1.y), packh2(b1.z, b1.w));
            }
#define DOT8(acc, wm, Um) \
            acc = fdot2f(wm.x, Um.x, 0.f);  acc = fdot2f(wm.y, Um.y, acc); \
            acc = fdot2f(wm.z, Um.z, acc);  acc = fdot2f(wm.w, Um.w, acc);
            const uint4 w0 = wq4[0], w1 = wq4[1];
            float A0, A1, B0, B1;
            DOT8(A0, w0, Ua) DOT8(A1, w1, Ua)
            DOT8(B0, w0, Ub) DOT8(B1, w1, Ub)
            const unsigned pa01 = packh2(A0, A1), pb01 = packh2(B0, B1);
            const uint4 w2 = wq4[2], w3 = wq4[3];
            float A2, A3, B2, B3;
            DOT8(A2, w2, Ua) DOT8(A3, w3, Ua)
            DOT8(B2, w2, Ub) DOT8(B3, w3, Ub)
            const unsigned pa23 = packh2(A2, A3), pb23 = packh2(B2, B3);
#undef DOT8
            sA01 += u2h(pa01);  sA23 += u2h(pa23);
            sB01 += u2h(pb01);  sB23 += u2h(pb23);
            const int dst = (i << 3) + pb;
            *(uint2*)&uh[dst]           = make_uint2(pa01, pa23);
            *(uint2*)&uh[TILE_DW + dst] = make_uint2(pb01, pb23);
        };
#pragma unroll
        for (int k = 0; k < 4; ++k) stage(i0 + 256 * k);
        if (i0 < IC - 1024) stage(i0 + 1024);

#pragma unroll
        for (int o = 4; o <= 32; o <<= 1) {
            sA01 += hshfl_xor(sA01, o);  sA23 += hshfl_xor(sA23, o);
            sB01 += hshfl_xor(sB01, o);  sB23 += hshfl_xor(sB23, o);
        }
        if (lane < 4) {   // lane == q here
            *(uint2*)&r0p[wid * 8 + (lane << 1)]       = make_uint2(h2u(sA01), h2u(sA23));
            *(uint2*)&r0p[128 + wid * 8 + (lane << 1)] = make_uint2(h2u(sB01), h2u(sB23));
        }
    }

    __syncthreads();  // B0

    // ---- Routing: octet w8 of batch bt owns rows [w8*144, +144) ----
    const int bt = wid >> 3;
    const int w8 = wid & 7;
    const int rowbase = w8 * 144;          // bit2 of rowbase == 0 -> eB math valid
    const unsigned* uhT = uh + bt * TILE_DW;

    const int cp = lane & 7;               // m-pair this lane combines/stores
    const int eB = (lane >> 2) & 1;        // row half-XOR parity (rows i1,i2,i3 share it)
    const int i1 = rowbase + lane, i2 = i1 + 64, i3 = rowbase + 128 + lane;

    float L0 = 0.f, L1 = 0.f, L2 = (lane < 16) ? 0.f : -1e30f;

    for (int r = 0; r < 3; ++r) {
        if (r == 2 && w8 != 0) break;      // only w8==0 produces output

        // ---- combine -> s -> squash -> v (per-lane m-pair cp) ----
        float sx, sy;
        {
            v2f s2 = {0.f, 0.f};
            float inv;
            if (r == 0) {
                h2 a2 = u2h(0u);
#pragma unroll
                for (int w = 0; w < 16; ++w)
                    a2 += u2h(r0p[bt * 128 + w * 8 + cp]);
                s2.x = (float)a2.x; s2.y = (float)a2.y;
                inv = 1.0f / (float)IC;
            } else {
                const int base = ((r - 1) & 1) * 160;
                float ses = 0.f;
#pragma unroll
                for (int w = 0; w < 8; ++w) {
                    const unsigned pw = spart[base + bt * 64 + w * 8 + cp];
                    const float2 mse = *(const float2*)&spart[base + 128 + (bt * 8 + w) * 2];
                    const float fac = __expf(mse.x);
                    const v2f pv = h_v2(pw);
                    s2.x += pv.x * fac;  s2.y += pv.y * fac;
                    ses += mse.y * fac;
                }
                inv = 1.0f / ses;
            }
            sx = s2.x * inv;  sy = s2.y * inv;
        }
        float p2 = sx * sx + sy * sy;
        p2 += __shfl_xor(p2, 1, 64);
        p2 += __shfl_xor(p2, 2, 64);
        p2 += __shfl_xor(p2, 4, 64);       // sum over the 8 pairs in the 8-group
        const float sc = p2 / ((1.0f + p2) * sqrtf(p2 + 1e-8f));
        const float vx = sx * sc, vy = sy * sc;

        if (r == 2) {
            if (lane < 8)
                *(float2*)&out[((size_t)(bb + bt) * OC + j) * 16 + (cp << 1)] =
                    make_float2(vx, vy);
            break;
        }

        // ---- broadcast v into position space (k ^ eB*4 gathers swizzled) ----
        const unsigned pk = packh2(vx, vy);
        unsigned vh[8];
        const int ebase = eB << 2;
#pragma unroll
        for (int k = 0; k < 8; ++k)
            vh[k] = (unsigned)__shfl((int)pk, k ^ ebase, 8);

        // ---- pass1: dp -> L (rows read in position space, matches vh) ----
#define DP8(Lk, ii) { \
        const uint4 da = *(const uint4*)&uhT[(ii) << 3]; \
        const uint4 db = *(const uint4*)&uhT[((ii) << 3) + 4]; \
        float d1 = fdot2f(da.x, vh[0], 0.f); d1 = fdot2f(da.y, vh[1], d1); \
        d1 = fdot2f(da.z, vh[2], d1); d1 = fdot2f(da.w, vh[3], d1); \
        float d2 = fdot2f(db.x, vh[4], 0.f); d2 = fdot2f(db.y, vh[5], d2); \
        d2 = fdot2f(db.z, vh[6], d2); d2 = fdot2f(db.w, vh[7], d2); \
        (Lk) += d1 + d2; }
        DP8(L0, i1)
        DP8(L1, i2)
        if (lane < 16) { DP8(L2, i3) }
#undef DP8

        // ---- wave max (range guard for f16 partials) ----
        float M = fmaxf(L0, fmaxf(L1, L2));
#pragma unroll
        for (int o = 32; o >= 1; o >>= 1)
            M = fmaxf(M, __shfl_xor(M, o, 64));

        // ---- pass2: ev = exp(L-M); se; s-partials via v_pk_fma_f16 ----
        h2 sa[8];
#pragma unroll
        for (int k = 0; k < 8; ++k) sa[k] = u2h(0u);
        float se = 0.f;
#define ROW2(Lk, ii) { \
        const uint4 da = *(const uint4*)&uhT[(ii) << 3]; \
        const uint4 db = *(const uint4*)&uhT[((ii) << 3) + 4]; \
        const float ev = __expf((Lk) - M); \
        se += ev; \
        const h2 eh = u2h(packh2(ev, ev)); \
        sa[0] += u2h(da.x) * eh;  sa[1] += u2h(da.y) * eh; \
        sa[2] += u2h(da.z) * eh;  sa[3] += u2h(da.w) * eh; \
        sa[4] += u2h(db.x) * eh;  sa[5] += u2h(db.y) * eh; \
        sa[6] += u2h(db.z) * eh;  sa[7] += u2h(db.w) * eh; }
        ROW2(L0, i1)
        ROW2(L1, i2)
        if (lane < 16) { ROW2(L2, i3) }
#undef ROW2
#pragma unroll
        for (int o = 32; o >= 1; o >>= 1)
            se += __shfl_xor(se, o, 64);

        // ---- narrowing XOR tree; step1 selects on (lane5 ^ eB) => m-space ----
        h2 tt;
        {
            const bool s5 = (((lane >> 5) & 1) ^ eB) != 0;
            const bool b4 = (lane & 16) != 0, b3 = (lane & 8) != 0;
            h2 tq[4];
#pragma unroll
            for (int q = 0; q < 4; ++q) {
                h2 snd = s5 ? sa[q] : sa[q + 4];
                tq[q] = (s5 ? sa[q + 4] : sa[q]) + hshfl_xor(snd, 32);
            }
            h2 uq[2];
#pragma unroll
            for (int q = 0; q < 2; ++q) {
                h2 snd = b4 ? tq[q] : tq[q + 2];
                uq[q] = (b4 ? tq[q + 2] : tq[q]) + hshfl_xor(snd, 16);
            }
            {
                h2 snd = b3 ? uq[0] : uq[1];
                tt = (b3 ? uq[1] : uq[0]) + hshfl_xor(snd, 8);
            }
            tt += hshfl_xor(tt, 4);
            tt += hshfl_xor(tt, 2);
            tt += hshfl_xor(tt, 1);
        }

        // ---- store partials: part[bt][w8][p] + Mse[bt][w8] ----
        const int po = (r & 1) * 160;
        if ((lane & 7) == 0)
            spart[po + bt * 64 + w8 * 8 + (lane >> 3)] = h2u(tt);
        if (lane == 1)
            *(float2*)&spart[po + 128 + (bt * 8 + w8) * 2] = make_float2(M, se);
        __syncthreads();  // B(r+1)
    }
}

extern "C" void kernel_launch(void* const* d_in, const int* in_sizes, int n_in,
                              void* d_out, int out_size, void* d_ws, size_t ws_size,
                              hipStream_t stream) {
    const float* u = (const float*)d_in[0];
    const float* W = (const float*)d_in[1];
    float* out = (float*)d_out;
    unsigned* ws = (unsigned*)d_ws;

    const int do_u = (ws_size >= WS_NEED) ? 1 : 0;
    const int total = NW_DW + (do_u ? NU_DW : 0);
    convert_kernel<<<(total + 255) / 256, 256, 0, stream>>>(u, W, ws, do_u);

    const size_t shmem = (size_t)(2 * TILE_DW + 256 + 320) * 4;  // 76032 B
    if (do_u) {
        hipFuncSetAttribute((const void*)caps_route_kernel<true>,
                            hipFuncAttributeMaxDynamicSharedMemorySize, (int)shmem);
        caps_route_kernel<true><<<(NB / 2) * OC, 1024, shmem, stream>>>(u, ws, ws + NW_DW, out);
    } else {
        hipFuncSetAttribute((const void*)caps_route_kernel<false>,
                            hipFuncAttributeMaxDynamicSharedMemorySize, (int)shmem);
        caps_route_kernel<false><<<(NB / 2) * OC, 1024, shmem, stream>>>(u, ws, ws + NW_DW, out);
    }
}

// Round 5
// 107.550 us; speedup vs baseline: 1.1573x; 1.0111x over previous
//
#include <hip/hip_runtime.h>
#include <hip/hip_bf16.h>
#include <math.h>

// CapsNet dynamic routing. R21 = R20 + serial reduces moved to DPP (VALU pipe).
// R20 post-mortem: wall = 1280 blocks x T / 512 resident (perfect packing);
// T ~ 19us = PhaseA ~5 + routing ~14. Routing throughput floors (DS 2.3us,
// VALU 1.7us per round) << measured ~7us/round -> serial-dependency bound:
// M/se/p2/tree shuffle chains on the DS pipe (~60cyc/step) + 8 serial expf
// in combine. R21:
//  - M-reduce, se-reduce: 6-step DPP row_shr/bcast ladder + readlane(63)
//    (~40cyc serial vs ~400; -12 DS ops/wave/round).
//  - p2: quad_perm DPP x2 + xor4 swizzle; tree tail xor2/xor1: quad_perm DPP.
//  - store (e^M_w, se_w): combine multiplies by the loaded factor -> the 8
//    serial expf/lane/round are gone (e^M f32-safe: raw-exp envelope R6-R18).
//  - v-broadcast: 8 compile-time ds_swizzle (and 0x1C | or k | xor k2) --
//    identical to the eB-XOR gather, no bpermute index setup.
// Math identical up to reassociation -> absmax expected 0.0039.
// Tripwires: VGPR == 32, WRITE_SIZE ~160KB, occupancy ~67%.
//
// u: [256][1152][8] f32; weight: [1152][10][8][16] f32; out: [256][10][16] f32

#define IC 1152
#define OC 10
#define NB 256
#define TILE_DW (IC * 8)              // dwords per batch tile (f16-packed)

#define NW_DW (IC * OC * 64)          // 737280 dwords: W as f16 n-pairs
#define NU_DW (NB * IC * 4)           // 1179648 dwords: u as f16 n-pairs
#define WS_NEED ((size_t)(NW_DW + NU_DW) * 4)

typedef float v2f __attribute__((ext_vector_type(2)));
typedef _Float16 h2 __attribute__((ext_vector_type(2)));

#if defined(__has_builtin)
#if __has_builtin(__builtin_amdgcn_fdot2)
#define HAVE_FDOT2 1
#endif
#endif

__device__ __forceinline__ float fdot2f(unsigned w, unsigned uu, float c) {
    h2 a = *(h2*)&w, b = *(h2*)&uu;
#ifdef HAVE_FDOT2
    return __builtin_amdgcn_fdot2(a, b, c, false);
#else
    return c + (float)a.x * (float)b.x + (float)a.y * (float)b.y;
#endif
}
__device__ __forceinline__ v2f h_v2(unsigned w) {
    h2 h = *(h2*)&w;
    v2f r = {(float)h.x, (float)h.y};
    return r;
}
__device__ __forceinline__ unsigned packh2(float a, float b) {
    h2 h = {(_Float16)a, (_Float16)b};
    return *(unsigned*)&h;
}
__device__ __forceinline__ unsigned h2u(h2 v) { return *(unsigned*)&v; }
__device__ __forceinline__ h2 u2h(unsigned v) { return *(h2*)&v; }
__device__ __forceinline__ h2 hshfl_xor(h2 v, int m) {
    unsigned b = *(unsigned*)&v;
    unsigned r = (unsigned)__shfl_xor((int)b, m, 64);
    return *(h2*)&r;
}

// ---- DPP reduce primitives (VALU pipe; ~4-8 cyc/step vs ~60 for ds_swizzle) ----
// row_shr:k = 0x110|k, row_bcast15 = 0x142, row_bcast31 = 0x143.
// bound_ctrl=false -> invalid lanes take OLD (identity: -inf for max, 0 for sum).
__device__ __forceinline__ float dpp_wave_max(float x) {
    int v = __float_as_int(x);
    int t;
#define MSTEP(ctrl) \
    t = __builtin_amdgcn_update_dpp(0xFF800000, v, (ctrl), 0xF, 0xF, false); \
    v = __float_as_int(fmaxf(__int_as_float(v), __int_as_float(t)));
    MSTEP(0x111) MSTEP(0x112) MSTEP(0x114) MSTEP(0x118) MSTEP(0x142) MSTEP(0x143)
#undef MSTEP
    return __int_as_float(__builtin_amdgcn_readlane(v, 63));
}
__device__ __forceinline__ float dpp_wave_sum(float x) {
    int v = __float_as_int(x);
    int t;
#define SSTEP(ctrl) \
    t = __builtin_amdgcn_update_dpp(0, v, (ctrl), 0xF, 0xF, false); \
    v = __float_as_int(__int_as_float(v) + __int_as_float(t));
    SSTEP(0x111) SSTEP(0x112) SSTEP(0x114) SSTEP(0x118) SSTEP(0x142) SSTEP(0x143)
#undef SSTEP
    return __int_as_float(__builtin_amdgcn_readlane(v, 63));
}
// quad_perm butterfly adds: xor1 = [1,0,3,2] = 0xB1, xor2 = [2,3,0,1] = 0x4E
template<int CTRL> __device__ __forceinline__ float qadd(float x) {
    int t = __builtin_amdgcn_update_dpp(0, __float_as_int(x), CTRL, 0xF, 0xF, false);
    return x + __int_as_float(t);
}
template<int CTRL> __device__ __forceinline__ h2 hqadd(h2 v) {
    int t = __builtin_amdgcn_update_dpp(0, (int)h2u(v), CTRL, 0xF, 0xF, false);
    return v + u2h((unsigned)t);
}

// ---- Pre-pass: W f32 -> f16 pairs along n, transposed; u f32 -> f16 pairs ----
// Wh dword e: kn=e&3 (n-pair), mp=(e>>2)&3, q=(e>>4)&3, ij=e>>6; m=q*4+mp
__global__ void convert_kernel(const float* __restrict__ u,
                               const float* __restrict__ W,
                               unsigned* __restrict__ ws, int do_u) {
    const int tid = blockIdx.x * blockDim.x + threadIdx.x;
    if (tid < NW_DW) {
        const int k = tid & 3, mp = (tid >> 2) & 3, q = (tid >> 4) & 3, ij = tid >> 6;
        const int m = (q << 2) + mp;
        const float* s = W + ((size_t)ij << 7) + m + (k << 5);
        ws[tid] = packh2(s[0], s[16]);
    } else if (do_u) {
        const int e = tid - NW_DW;
        if (e < NU_DW) {
            const int pr = e & 3, bi = e >> 2;
            const float* s = u + ((size_t)bi << 3) + (pr << 1);
            ws[NW_DW + e] = packh2(s[0], s[1]);
        }
    }
}

template<bool UF16>
__global__ __launch_bounds__(1024, 8)
void caps_route_kernel(const float* __restrict__ u,
                       const unsigned* __restrict__ Wh,
                       const unsigned* __restrict__ ug,
                       float* __restrict__ out) {
    extern __shared__ unsigned smem_u[];
    unsigned* uh   = smem_u;                 // 2 tiles (73728 B)
    unsigned* r0p  = uh + 2 * TILE_DW;       // [2 bt][16 wid][8 dw] f16 (1024 B)
    unsigned* spart = r0p + 256;             // [2 par][part 128 | expM,se 32] (1280 B)

    const int t    = threadIdx.x;
    const int bx   = blockIdx.x;
    const int lane = t & 63;
    const int wid  = t >> 6;

    // XCD-aware (j, batch-pair) mapping (xcd = bx & 7 heuristic).
    int x = bx & 7, sg = bx >> 3;
    int j, p;
    if (sg < 128) { j = x; p = sg; }
    else { int s2v = sg - 128; j = 8 + (x >> 2); p = ((x & 3) << 5) + s2v; }
    const int bb = p * 2;  // batches bb, bb+1

    // ---- Phase A: uhat -> LDS f16 (half-XOR swizzle) + r0 column sums ----
    // (R18-proven structure; pairwise W loads keep the 32-VGPR wall.)
    {
        const int q  = t & 3;
        const int i0 = t >> 2;           // 0..255
        const int pb = (((q >> 1) ^ ((i0 >> 2) & 1)) << 2) + ((q & 1) << 1);
        const float* u0p = u + (size_t)bb * (IC * 8);
        const uint4* ua4 = (const uint4*)ug + (size_t)bb * IC;
        const uint4* ub4 = ua4 + IC;

        h2 sA01 = u2h(0u), sA23 = u2h(0u);
        h2 sB01 = u2h(0u), sB23 = u2h(0u);

        auto stage = [&](int i) {
            const uint4* wq4 = (const uint4*)Wh + (((size_t)(i * OC + j) << 2) + q) * 4;
            uint4 Ua, Ub;
            if constexpr (UF16) {
                Ua = ua4[i];
                Ub = ub4[i];
            } else {
                const float4 a0 = *(const float4*)(u0p + i * 8);
                const float4 a1 = *(const float4*)(u0p + i * 8 + 4);
                const float4 b0 = *(const float4*)(u0p + IC * 8 + i * 8);
                const float4 b1 = *(const float4*)(u0p + IC * 8 + i * 8 + 4);
                Ua = make_uint4(packh2(a0.x, a0.y), packh2(a0.z, a0.w),
                                packh2(a1.x, a1.y), packh2(a1.z, a1.w));
                Ub = make_uint4(packh2(b0.x, b0.y), packh2(b0.z, b0.w),
                                packh2(b1.x, b1.y), packh2(b1.z, b1.w));
            }
#define DOT8(acc, wm, Um) \
            acc = fdot2f(wm.x, Um.x, 0.f);  acc = fdot2f(wm.y, Um.y, acc); \
            acc = fdot2f(wm.z, Um.z, acc);  acc = fdot2f(wm.w, Um.w, acc);
            const uint4 w0 = wq4[0], w1 = wq4[1];
            float A0, A1, B0, B1;
            DOT8(A0, w0, Ua) DOT8(A1, w1, Ua)
            DOT8(B0, w0, Ub) DOT8(B1, w1, Ub)
            const unsigned pa01 = packh2(A0, A1), pb01 = packh2(B0, B1);
            const uint4 w2 = wq4[2], w3 = wq4[3];
            float A2, A3, B2, B3;
            DOT8(A2, w2, Ua) DOT8(A3, w3, Ua)
            DOT8(B2, w2, Ub) DOT8(B3, w3, Ub)
            const unsigned pa23 = packh2(A2, A3), pb23 = packh2(B2, B3);
#undef DOT8
            sA01 += u2h(pa01);  sA23 += u2h(pa23);
            sB01 += u2h(pb01);  sB23 += u2h(pb23);
            const int dst = (i << 3) + pb;
            *(uint2*)&uh[dst]           = make_uint2(pa01, pa23);
            *(uint2*)&uh[TILE_DW + dst] = make_uint2(pb01, pb23);
        };
#pragma unroll
        for (int k = 0; k < 4; ++k) stage(i0 + 256 * k);
        if (i0 < IC - 1024) stage(i0 + 1024);

#pragma unroll
        for (int o = 4; o <= 32; o <<= 1) {
            sA01 += hshfl_xor(sA01, o);  sA23 += hshfl_xor(sA23, o);
            sB01 += hshfl_xor(sB01, o);  sB23 += hshfl_xor(sB23, o);
        }
        if (lane < 4) {   // lane == q here
            *(uint2*)&r0p[wid * 8 + (lane << 1)]       = make_uint2(h2u(sA01), h2u(sA23));
            *(uint2*)&r0p[128 + wid * 8 + (lane << 1)] = make_uint2(h2u(sB01), h2u(sB23));
        }
    }

    __syncthreads();  // B0

    // ---- Routing: octet w8 of batch bt owns rows [w8*144, +144) ----
    const int bt = wid >> 3;
    const int w8 = wid & 7;
    const int rowbase = w8 * 144;          // bit2 of rowbase == 0 -> eB math valid
    const unsigned* uhT = uh + bt * TILE_DW;

    const int cp = lane & 7;               // m-pair this lane combines/stores
    const int i1 = rowbase + lane, i2 = i1 + 64, i3 = rowbase + 128 + lane;

    float L0 = 0.f, L1 = 0.f, L2 = (lane < 16) ? 0.f : -1e30f;

    for (int r = 0; r < 3; ++r) {
        if (r == 2 && w8 != 0) break;      // only w8==0 produces output

        // ---- combine -> s -> squash -> v (per-lane m-pair cp) ----
        float sx, sy;
        {
            v2f s2 = {0.f, 0.f};
            float inv;
            if (r == 0) {
                h2 a2 = u2h(0u);
#pragma unroll
                for (int w = 0; w < 16; ++w)
                    a2 += u2h(r0p[bt * 128 + w * 8 + cp]);
                s2.x = (float)a2.x; s2.y = (float)a2.y;
                inv = 1.0f / (float)IC;
            } else {
                const int base = ((r - 1) & 1) * 160;
                float ses = 0.f;
#pragma unroll
                for (int w = 0; w < 8; ++w) {
                    const unsigned pw = spart[base + bt * 64 + w * 8 + cp];
                    const float2 mse = *(const float2*)&spart[base + 128 + (bt * 8 + w) * 2];
                    const float fac = mse.x;           // e^{M_w} precomputed at store
                    const v2f pv = h_v2(pw);
                    s2.x += pv.x * fac;  s2.y += pv.y * fac;
                    ses += mse.y * fac;
                }
                inv = 1.0f / ses;
            }
            sx = s2.x * inv;  sy = s2.y * inv;
        }
        float p2 = sx * sx + sy * sy;
        p2 = qadd<0xB1>(p2);               // xor1 (quad_perm, VALU)
        p2 = qadd<0x4E>(p2);               // xor2
        p2 += __int_as_float(__builtin_amdgcn_ds_swizzle(__float_as_int(p2), 0x101F)); // xor4
        const float sc = p2 / ((1.0f + p2) * sqrtf(p2 + 1e-8f));
        const float vx = sx * sc, vy = sy * sc;

        if (r == 2) {
            if (lane < 8)
                *(float2*)&out[((size_t)(bb + bt) * OC + j) * 16 + (cp << 1)] =
                    make_float2(vx, vy);
            break;
        }

        // ---- broadcast v into position space: compile-time ds_swizzle ----
        // src = (l & 0x1C) | (k & 3), bit2 ^= k2  ==  __shfl(pk, k ^ (l&4), 8)
        const int pki = (int)packh2(vx, vy);
        unsigned vh[8];
        vh[0] = (unsigned)__builtin_amdgcn_ds_swizzle(pki, 0x001C);
        vh[1] = (unsigned)__builtin_amdgcn_ds_swizzle(pki, 0x003C);
        vh[2] = (unsigned)__builtin_amdgcn_ds_swizzle(pki, 0x005C);
        vh[3] = (unsigned)__builtin_amdgcn_ds_swizzle(pki, 0x007C);
        vh[4] = (unsigned)__builtin_amdgcn_ds_swizzle(pki, 0x101C);
        vh[5] = (unsigned)__builtin_amdgcn_ds_swizzle(pki, 0x103C);
        vh[6] = (unsigned)__builtin_amdgcn_ds_swizzle(pki, 0x105C);
        vh[7] = (unsigned)__builtin_amdgcn_ds_swizzle(pki, 0x107C);

        // ---- pass1: dp -> L (rows read in position space, matches vh) ----
#define DP8(Lk, ii) { \
        const uint4 da = *(const uint4*)&uhT[(ii) << 3]; \
        const uint4 db = *(const uint4*)&uhT[((ii) << 3) + 4]; \
        float d1 = fdot2f(da.x, vh[0], 0.f); d1 = fdot2f(da.y, vh[1], d1); \
        d1 = fdot2f(da.z, vh[2], d1); d1 = fdot2f(da.w, vh[3], d1); \
        float d2 = fdot2f(db.x, vh[4], 0.f); d2 = fdot2f(db.y, vh[5], d2); \
        d2 = fdot2f(db.z, vh[6], d2); d2 = fdot2f(db.w, vh[7], d2); \
        (Lk) += d1 + d2; }
        DP8(L0, i1)
        DP8(L1, i2)
        if (lane < 16) { DP8(L2, i3) }
#undef DP8

        // ---- wave max via DPP ladder (range guard for f16 partials) ----
        const float M = dpp_wave_max(fmaxf(L0, fmaxf(L1, L2)));

        // ---- pass2: ev = exp(L-M); se; s-partials via v_pk_fma_f16 ----
        h2 sa[8];
#pragma unroll
        for (int k = 0; k < 8; ++k) sa[k] = u2h(0u);
        float sel = 0.f;
#define ROW2(Lk, ii) { \
        const uint4 da = *(const uint4*)&uhT[(ii) << 3]; \
        const uint4 db = *(const uint4*)&uhT[((ii) << 3) + 4]; \
        const float ev = __expf((Lk) - M); \
        sel += ev; \
        const h2 eh = u2h(packh2(ev, ev)); \
        sa[0] += u2h(da.x) * eh;  sa[1] += u2h(da.y) * eh; \
        sa[2] += u2h(da.z) * eh;  sa[3] += u2h(da.w) * eh; \
        sa[4] += u2h(db.x) * eh;  sa[5] += u2h(db.y) * eh; \
        sa[6] += u2h(db.z) * eh;  sa[7] += u2h(db.w) * eh; }
        ROW2(L0, i1)
        ROW2(L1, i2)
        if (lane < 16) { ROW2(L2, i3) }
#undef ROW2
        const float se = dpp_wave_sum(sel);   // VALU ladder, overlaps the DS tree

        // ---- narrowing XOR tree; step1 selects on (lane5 ^ eB) => m-space ----
        h2 tt;
        {
            const int eB = (lane >> 2) & 1;
            const bool s5 = (((lane >> 5) & 1) ^ eB) != 0;
            const bool b4 = (lane & 16) != 0, b3 = (lane & 8) != 0;
            h2 tq[4];
#pragma unroll
            for (int q = 0; q < 4; ++q) {
                h2 snd = s5 ? sa[q] : sa[q + 4];
                tq[q] = (s5 ? sa[q + 4] : sa[q]) + hshfl_xor(snd, 32);
            }
            h2 uq[2];
#pragma unroll
            for (int q = 0; q < 2; ++q) {
                h2 snd = b4 ? tq[q] : tq[q + 2];
                uq[q] = (b4 ? tq[q + 2] : tq[q]) + hshfl_xor(snd, 16);
            }
            {
                h2 snd = b3 ? uq[0] : uq[1];
                tt = (b3 ? uq[1] : uq[0]) + hshfl_xor(snd, 8);
            }
            tt += u2h((unsigned)__builtin_amdgcn_ds_swizzle((int)h2u(tt), 0x101F)); // xor4
            tt = hqadd<0x4E>(tt);          // xor2 (quad_perm)
            tt = hqadd<0xB1>(tt);          // xor1
        }

        // ---- store partials: part[bt][w8][p] + (e^M, se)[bt][w8] ----
        const int po = (r & 1) * 160;
        if ((lane & 7) == 0)
            spart[po + bt * 64 + w8 * 8 + (lane >> 3)] = h2u(tt);
        if (lane == 1)
            *(float2*)&spart[po + 128 + (bt * 8 + w8) * 2] = make_float2(__expf(M), se);
        __syncthreads();  // B(r+1)
    }
}

extern "C" void kernel_launch(void* const* d_in, const int* in_sizes, int n_in,
                              void* d_out, int out_size, void* d_ws, size_t ws_size,
                              hipStream_t stream) {
    const float* u = (const float*)d_in[0];
    const float* W = (const float*)d_in[1];
    float* out = (float*)d_out;
    unsigned* ws = (unsigned*)d_ws;

    const int do_u = (ws_size >= WS_NEED) ? 1 : 0;
    const int total = NW_DW + (do_u ? NU_DW : 0);
    convert_kernel<<<(total + 255) / 256, 256, 0, stream>>>(u, W, ws, do_u);

    const size_t shmem = (size_t)(2 * TILE_DW + 256 + 320) * 4;  // 76032 B
    if (do_u) {
        hipFuncSetAttribute((const void*)caps_route_kernel<true>,
                            hipFuncAttributeMaxDynamicSharedMemorySize, (int)shmem);
        caps_route_kernel<true><<<(NB / 2) * OC, 1024, shmem, stream>>>(u, ws, ws + NW_DW, out);
    } else {
        hipFuncSetAttribute((const void*)caps_route_kernel<false>,
                            hipFuncAttributeMaxDynamicSharedMemorySize, (int)shmem);
        caps_route_kernel<false><<<(NB / 2) * OC, 1024, shmem, stream>>>(u, ws, ws + NW_DW, out);
    }
}

// Round 6
// 107.193 us; speedup vs baseline: 1.1611x; 1.0033x over previous
//
#include <hip/hip_runtime.h>
#include <hip/hip_bf16.h>
#include <math.h>

// CapsNet dynamic routing. R22 = R21 + per-batch flag sync (barrier convoy fix).
// R21 post-mortem: wall 46us ~= SUM of per-CU pipe budgets (W-L2 11.5 + DS 9
// + VALU 16) not their max -> the 2 inter-round __syncthreads lock all 32
// resident waves into identical phases (combine DS burst / dp VALU burst /
// tree DS burst), serializing the pipes. But round partials only couple the
// 8 octet-waves of ONE batch. R22: replace inter-round barriers with
// per-batch LDS counters: octet bumps flags[bt] after lgkmcnt(0)-drained
// stores; combine spins (volatile broadcast read + s_sleep) for 8*r bumps.
//  - parity-0/1 spart written exactly once each (no WAR); bumps
//    unconditional for r=0,1 -> no deadlock; skew within batch <= 1 phase.
//  - batches drift -> DS/VALU phases interleave; w8!=0 waves retire after
//    r1 bump, freeing SIMD slots for the co-resident block.
// Math identical to R21 -> absmax expected 0.00390625 exactly.
// Tripwires: VGPR == 32, WRITE_SIZE ~160KB, no hang (flag logic).
//
// u: [256][1152][8] f32; weight: [1152][10][8][16] f32; out: [256][10][16] f32

#define IC 1152
#define OC 10
#define NB 256
#define TILE_DW (IC * 8)              // dwords per batch tile (f16-packed)

#define NW_DW (IC * OC * 64)          // 737280 dwords: W as f16 n-pairs
#define NU_DW (NB * IC * 4)           // 1179648 dwords: u as f16 n-pairs
#define WS_NEED ((size_t)(NW_DW + NU_DW) * 4)

typedef float v2f __attribute__((ext_vector_type(2)));
typedef _Float16 h2 __attribute__((ext_vector_type(2)));

#if defined(__has_builtin)
#if __has_builtin(__builtin_amdgcn_fdot2)
#define HAVE_FDOT2 1
#endif
#endif

__device__ __forceinline__ float fdot2f(unsigned w, unsigned uu, float c) {
    h2 a = *(h2*)&w, b = *(h2*)&uu;
#ifdef HAVE_FDOT2
    return __builtin_amdgcn_fdot2(a, b, c, false);
#else
    return c + (float)a.x * (float)b.x + (float)a.y * (float)b.y;
#endif
}
__device__ __forceinline__ v2f h_v2(unsigned w) {
    h2 h = *(h2*)&w;
    v2f r = {(float)h.x, (float)h.y};
    return r;
}
__device__ __forceinline__ unsigned packh2(float a, float b) {
    h2 h = {(_Float16)a, (_Float16)b};
    return *(unsigned*)&h;
}
__device__ __forceinline__ unsigned h2u(h2 v) { return *(unsigned*)&v; }
__device__ __forceinline__ h2 u2h(unsigned v) { return *(h2*)&v; }
__device__ __forceinline__ h2 hshfl_xor(h2 v, int m) {
    unsigned b = *(unsigned*)&v;
    unsigned r = (unsigned)__shfl_xor((int)b, m, 64);
    return *(h2*)&r;
}

// ---- DPP reduce primitives (VALU pipe) ----
__device__ __forceinline__ float dpp_wave_max(float x) {
    int v = __float_as_int(x);
    int t;
#define MSTEP(ctrl) \
    t = __builtin_amdgcn_update_dpp(0xFF800000, v, (ctrl), 0xF, 0xF, false); \
    v = __float_as_int(fmaxf(__int_as_float(v), __int_as_float(t)));
    MSTEP(0x111) MSTEP(0x112) MSTEP(0x114) MSTEP(0x118) MSTEP(0x142) MSTEP(0x143)
#undef MSTEP
    return __int_as_float(__builtin_amdgcn_readlane(v, 63));
}
__device__ __forceinline__ float dpp_wave_sum(float x) {
    int v = __float_as_int(x);
    int t;
#define SSTEP(ctrl) \
    t = __builtin_amdgcn_update_dpp(0, v, (ctrl), 0xF, 0xF, false); \
    v = __float_as_int(__int_as_float(v) + __int_as_float(t));
    SSTEP(0x111) SSTEP(0x112) SSTEP(0x114) SSTEP(0x118) SSTEP(0x142) SSTEP(0x143)
#undef SSTEP
    return __int_as_float(__builtin_amdgcn_readlane(v, 63));
}
template<int CTRL> __device__ __forceinline__ float qadd(float x) {
    int t = __builtin_amdgcn_update_dpp(0, __float_as_int(x), CTRL, 0xF, 0xF, false);
    return x + __int_as_float(t);
}
template<int CTRL> __device__ __forceinline__ h2 hqadd(h2 v) {
    int t = __builtin_amdgcn_update_dpp(0, (int)h2u(v), CTRL, 0xF, 0xF, false);
    return v + u2h((unsigned)t);
}

// ---- Pre-pass: W f32 -> f16 pairs along n, transposed; u f32 -> f16 pairs ----
__global__ void convert_kernel(const float* __restrict__ u,
                               const float* __restrict__ W,
                               unsigned* __restrict__ ws, int do_u) {
    const int tid = blockIdx.x * blockDim.x + threadIdx.x;
    if (tid < NW_DW) {
        const int k = tid & 3, mp = (tid >> 2) & 3, q = (tid >> 4) & 3, ij = tid >> 6;
        const int m = (q << 2) + mp;
        const float* s = W + ((size_t)ij << 7) + m + (k << 5);
        ws[tid] = packh2(s[0], s[16]);
    } else if (do_u) {
        const int e = tid - NW_DW;
        if (e < NU_DW) {
            const int pr = e & 3, bi = e >> 2;
            const float* s = u + ((size_t)bi << 3) + (pr << 1);
            ws[NW_DW + e] = packh2(s[0], s[1]);
        }
    }
}

template<bool UF16>
__global__ __launch_bounds__(1024, 8)
void caps_route_kernel(const float* __restrict__ u,
                       const unsigned* __restrict__ Wh,
                       const unsigned* __restrict__ ug,
                       float* __restrict__ out) {
    extern __shared__ unsigned smem_u[];
    unsigned* uh    = smem_u;                // 2 tiles (73728 B)
    unsigned* r0p   = uh + 2 * TILE_DW;      // [2 bt][16 wid][8 dw] f16 (1024 B)
    unsigned* spart = r0p + 256;             // [2 par][part 128 | expM,se 32] (1280 B)
    unsigned* flags = spart + 320;           // [2 bt] round counters (8 B)

    const int t    = threadIdx.x;
    const int bx   = blockIdx.x;
    const int lane = t & 63;
    const int wid  = t >> 6;

    // XCD-aware (j, batch-pair) mapping (xcd = bx & 7 heuristic).
    int x = bx & 7, sg = bx >> 3;
    int j, p;
    if (sg < 128) { j = x; p = sg; }
    else { int s2v = sg - 128; j = 8 + (x >> 2); p = ((x & 3) << 5) + s2v; }
    const int bb = p * 2;  // batches bb, bb+1

    if (t < 2) flags[t] = 0u;

    // ---- Phase A: uhat -> LDS f16 (half-XOR swizzle) + r0 column sums ----
    {
        const int q  = t & 3;
        const int i0 = t >> 2;           // 0..255
        const int pb = (((q >> 1) ^ ((i0 >> 2) & 1)) << 2) + ((q & 1) << 1);
        const float* u0p = u + (size_t)bb * (IC * 8);
        const uint4* ua4 = (const uint4*)ug + (size_t)bb * IC;
        const uint4* ub4 = ua4 + IC;

        h2 sA01 = u2h(0u), sA23 = u2h(0u);
        h2 sB01 = u2h(0u), sB23 = u2h(0u);

        auto stage = [&](int i) {
            const uint4* wq4 = (const uint4*)Wh + (((size_t)(i * OC + j) << 2) + q) * 4;
            uint4 Ua, Ub;
            if constexpr (UF16) {
                Ua = ua4[i];
                Ub = ub4[i];
            } else {
                const float4 a0 = *(const float4*)(u0p + i * 8);
                const float4 a1 = *(const float4*)(u0p + i * 8 + 4);
                const float4 b0 = *(const float4*)(u0p + IC * 8 + i * 8);
                const float4 b1 = *(const float4*)(u0p + IC * 8 + i * 8 + 4);
                Ua = make_uint4(packh2(a0.x, a0.y), packh2(a0.z, a0.w),
                                packh2(a1.x, a1.y), packh2(a1.z, a1.w));
                Ub = make_uint4(packh2(b0.x, b0.y), packh2(b0.z, b0.w),
                                packh2(b1.x, b1.y), packh2(b1.z, b1.w));
            }
#define DOT8(acc, wm, Um) \
            acc = fdot2f(wm.x, Um.x, 0.f);  acc = fdot2f(wm.y, Um.y, acc); \
            acc = fdot2f(wm.z, Um.z, acc);  acc = fdot2f(wm.w, Um.w, acc);
            const uint4 w0 = wq4[0], w1 = wq4[1];
            float A0, A1, B0, B1;
            DOT8(A0, w0, Ua) DOT8(A1, w1, Ua)
            DOT8(B0, w0, Ub) DOT8(B1, w1, Ub)
            const unsigned pa01 = packh2(A0, A1), pb01 = packh2(B0, B1);
            const uint4 w2 = wq4[2], w3 = wq4[3];
            float A2, A3, B2, B3;
            DOT8(A2, w2, Ua) DOT8(A3, w3, Ua)
            DOT8(B2, w2, Ub) DOT8(B3, w3, Ub)
            const unsigned pa23 = packh2(A2, A3), pb23 = packh2(B2, B3);
#undef DOT8
            sA01 += u2h(pa01);  sA23 += u2h(pa23);
            sB01 += u2h(pb01);  sB23 += u2h(pb23);
            const int dst = (i << 3) + pb;
            *(uint2*)&uh[dst]           = make_uint2(pa01, pa23);
            *(uint2*)&uh[TILE_DW + dst] = make_uint2(pb01, pb23);
        };
#pragma unroll
        for (int k = 0; k < 4; ++k) stage(i0 + 256 * k);
        if (i0 < IC - 1024) stage(i0 + 1024);

#pragma unroll
        for (int o = 4; o <= 32; o <<= 1) {
            sA01 += hshfl_xor(sA01, o);  sA23 += hshfl_xor(sA23, o);
            sB01 += hshfl_xor(sB01, o);  sB23 += hshfl_xor(sB23, o);
        }
        if (lane < 4) {   // lane == q here
            *(uint2*)&r0p[wid * 8 + (lane << 1)]       = make_uint2(h2u(sA01), h2u(sA23));
            *(uint2*)&r0p[128 + wid * 8 + (lane << 1)] = make_uint2(h2u(sB01), h2u(sB23));
        }
    }

    __syncthreads();  // B0: uhat + r0 partials + flag init ready

    // ---- Routing: octet w8 of batch bt owns rows [w8*144, +144) ----
    const int bt = wid >> 3;
    const int w8 = wid & 7;
    const int rowbase = w8 * 144;          // bit2 of rowbase == 0 -> eB math valid
    const unsigned* uhT = uh + bt * TILE_DW;

    const int cp = lane & 7;               // m-pair this lane combines/stores
    const int i1 = rowbase + lane, i2 = i1 + 64, i3 = rowbase + 128 + lane;

    float L0 = 0.f, L1 = 0.f, L2 = (lane < 16) ? 0.f : -1e30f;

    for (int r = 0; r < 3; ++r) {
        if (r == 2 && w8 != 0) break;      // only w8==0 produces output

        // ---- wait for this batch's round-(r-1) partials (flag sync) ----
        if (r > 0) {
            const unsigned tgt = 8u * (unsigned)r;
            volatile unsigned* fl = (volatile unsigned*)&flags[bt];
            while (*fl < tgt) __builtin_amdgcn_s_sleep(1);
            asm volatile("" ::: "memory");
        }

        // ---- combine -> s -> squash -> v (per-lane m-pair cp) ----
        float sx, sy;
        {
            v2f s2 = {0.f, 0.f};
            float inv;
            if (r == 0) {
                h2 a2 = u2h(0u);
#pragma unroll
                for (int w = 0; w < 16; ++w)
                    a2 += u2h(r0p[bt * 128 + w * 8 + cp]);
                s2.x = (float)a2.x; s2.y = (float)a2.y;
                inv = 1.0f / (float)IC;
            } else {
                const int base = ((r - 1) & 1) * 160;
                float ses = 0.f;
#pragma unroll
                for (int w = 0; w < 8; ++w) {
                    const unsigned pw = spart[base + bt * 64 + w * 8 + cp];
                    const float2 mse = *(const float2*)&spart[base + 128 + (bt * 8 + w) * 2];
                    const float fac = mse.x;           // e^{M_w} precomputed at store
                    const v2f pv = h_v2(pw);
                    s2.x += pv.x * fac;  s2.y += pv.y * fac;
                    ses += mse.y * fac;
                }
                inv = 1.0f / ses;
            }
            sx = s2.x * inv;  sy = s2.y * inv;
        }
        float p2 = sx * sx + sy * sy;
        p2 = qadd<0xB1>(p2);               // xor1 (quad_perm, VALU)
        p2 = qadd<0x4E>(p2);               // xor2
        p2 += __int_as_float(__builtin_amdgcn_ds_swizzle(__float_as_int(p2), 0x101F)); // xor4
        const float sc = p2 / ((1.0f + p2) * sqrtf(p2 + 1e-8f));
        const float vx = sx * sc, vy = sy * sc;

        if (r == 2) {
            if (lane < 8)
                *(float2*)&out[((size_t)(bb + bt) * OC + j) * 16 + (cp << 1)] =
                    make_float2(vx, vy);
            break;
        }

        // ---- broadcast v into position space: compile-time ds_swizzle ----
        const int pki = (int)packh2(vx, vy);
        unsigned vh[8];
        vh[0] = (unsigned)__builtin_amdgcn_ds_swizzle(pki, 0x001C);
        vh[1] = (unsigned)__builtin_amdgcn_ds_swizzle(pki, 0x003C);
        vh[2] = (unsigned)__builtin_amdgcn_ds_swizzle(pki, 0x005C);
        vh[3] = (unsigned)__builtin_amdgcn_ds_swizzle(pki, 0x007C);
        vh[4] = (unsigned)__builtin_amdgcn_ds_swizzle(pki, 0x101C);
        vh[5] = (unsigned)__builtin_amdgcn_ds_swizzle(pki, 0x103C);
        vh[6] = (unsigned)__builtin_amdgcn_ds_swizzle(pki, 0x105C);
        vh[7] = (unsigned)__builtin_amdgcn_ds_swizzle(pki, 0x107C);

        // ---- pass1: dp -> L ----
#define DP8(Lk, ii) { \
        const uint4 da = *(const uint4*)&uhT[(ii) << 3]; \
        const uint4 db = *(const uint4*)&uhT[((ii) << 3) + 4]; \
        float d1 = fdot2f(da.x, vh[0], 0.f); d1 = fdot2f(da.y, vh[1], d1); \
        d1 = fdot2f(da.z, vh[2], d1); d1 = fdot2f(da.w, vh[3], d1); \
        float d2 = fdot2f(db.x, vh[4], 0.f); d2 = fdot2f(db.y, vh[5], d2); \
        d2 = fdot2f(db.z, vh[6], d2); d2 = fdot2f(db.w, vh[7], d2); \
        (Lk) += d1 + d2; }
        DP8(L0, i1)
        DP8(L1, i2)
        if (lane < 16) { DP8(L2, i3) }
#undef DP8

        // ---- wave max via DPP ladder (range guard for f16 partials) ----
        const float M = dpp_wave_max(fmaxf(L0, fmaxf(L1, L2)));

        // ---- pass2: ev = exp(L-M); se; s-partials via v_pk_fma_f16 ----
        h2 sa[8];
#pragma unroll
        for (int k = 0; k < 8; ++k) sa[k] = u2h(0u);
        float sel = 0.f;
#define ROW2(Lk, ii) { \
        const uint4 da = *(const uint4*)&uhT[(ii) << 3]; \
        const uint4 db = *(const uint4*)&uhT[((ii) << 3) + 4]; \
        const float ev = __expf((Lk) - M); \
        sel += ev; \
        const h2 eh = u2h(packh2(ev, ev)); \
        sa[0] += u2h(da.x) * eh;  sa[1] += u2h(da.y) * eh; \
        sa[2] += u2h(da.z) * eh;  sa[3] += u2h(da.w) * eh; \
        sa[4] += u2h(db.x) * eh;  sa[5] += u2h(db.y) * eh; \
        sa[6] += u2h(db.z) * eh;  sa[7] += u2h(db.w) * eh; }
        ROW2(L0, i1)
        ROW2(L1, i2)
        if (lane < 16) { ROW2(L2, i3) }
#undef ROW2
        const float se = dpp_wave_sum(sel);

        // ---- narrowing XOR tree; step1 selects on (lane5 ^ eB) => m-space ----
        h2 tt;
        {
            const int eB = (lane >> 2) & 1;
            const bool s5 = (((lane >> 5) & 1) ^ eB) != 0;
            const bool b4 = (lane & 16) != 0, b3 = (lane & 8) != 0;
            h2 tq[4];
#pragma unroll
            for (int q = 0; q < 4; ++q) {
                h2 snd = s5 ? sa[q] : sa[q + 4];
                tq[q] = (s5 ? sa[q + 4] : sa[q]) + hshfl_xor(snd, 32);
            }
            h2 uq[2];
#pragma unroll
            for (int q = 0; q < 2; ++q) {
                h2 snd = b4 ? tq[q] : tq[q + 2];
                uq[q] = (b4 ? tq[q + 2] : tq[q]) + hshfl_xor(snd, 16);
            }
            {
                h2 snd = b3 ? uq[0] : uq[1];
                tt = (b3 ? uq[1] : uq[0]) + hshfl_xor(snd, 8);
            }
            tt += u2h((unsigned)__builtin_amdgcn_ds_swizzle((int)h2u(tt), 0x101F)); // xor4
            tt = hqadd<0x4E>(tt);          // xor2 (quad_perm)
            tt = hqadd<0xB1>(tt);          // xor1
        }

        // ---- store partials, drain LDS, bump this batch's round counter ----
        const int po = (r & 1) * 160;
        if ((lane & 7) == 0)
            spart[po + bt * 64 + w8 * 8 + (lane >> 3)] = h2u(tt);
        if (lane == 1)
            *(float2*)&spart[po + 128 + (bt * 8 + w8) * 2] = make_float2(__expf(M), se);
        asm volatile("s_waitcnt lgkmcnt(0)" ::: "memory");
        if (lane == 0) atomicAdd(&flags[bt], 1u);
    }
}

extern "C" void kernel_launch(void* const* d_in, const int* in_sizes, int n_in,
                              void* d_out, int out_size, void* d_ws, size_t ws_size,
                              hipStream_t stream) {
    const float* u = (const float*)d_in[0];
    const float* W = (const float*)d_in[1];
    float* out = (float*)d_out;
    unsigned* ws = (unsigned*)d_ws;

    const int do_u = (ws_size >= WS_NEED) ? 1 : 0;
    const int total = NW_DW + (do_u ? NU_DW : 0);
    convert_kernel<<<(total + 255) / 256, 256, 0, stream>>>(u, W, ws, do_u);

    const size_t shmem = (size_t)(2 * TILE_DW + 256 + 320 + 2) * 4;  // 76040 B
    if (do_u) {
        hipFuncSetAttribute((const void*)caps_route_kernel<true>,
                            hipFuncAttributeMaxDynamicSharedMemorySize, (int)shmem);
        caps_route_kernel<true><<<(NB / 2) * OC, 1024, shmem, stream>>>(u, ws, ws + NW_DW, out);
    } else {
        hipFuncSetAttribute((const void*)caps_route_kernel<false>,
                            hipFuncAttributeMaxDynamicSharedMemorySize, (int)shmem);
        caps_route_kernel<false><<<(NB / 2) * OC, 1024, shmem, stream>>>(u, ws, ws + NW_DW, out);
    }
}

// Round 7
// 106.947 us; speedup vs baseline: 1.1638x; 1.0023x over previous
//
#include <hip/hip_runtime.h>
#include <hip/hip_bf16.h>
#include <math.h>

// CapsNet dynamic routing. R23 = R21 main kernel (exact revert of R22's
// flag-sync regression: spin-poll cost > convoy gain) + vectorized convert.
// R22 post-mortem: barriers back; flag/spin removed.
// Convert analysis: bench-gap R16 (no convert) 49.8us vs R17+ ~61us ->
// convert ~11us, dominated by scalar strided W reads (2 f32 loads 64B apart,
// thread stride 128B). R23 convert: W-thread = 2x float4 reads -> 4 packed
// dwords (bit-identical layout/values); u-thread = 1 coalesced float4 ->
// uint2. Threads 1.92M -> 0.77M, all reads 16B vectors. Predicted ~4-5us.
// Tripwires: VGPR == 32, WRITE_SIZE ~160KB, absmax == 0.00390625,
// bench gap shrinks >= 4us.
//
// u: [256][1152][8] f32; weight: [1152][10][8][16] f32; out: [256][10][16] f32

#define IC 1152
#define OC 10
#define NB 256
#define TILE_DW (IC * 8)              // dwords per batch tile (f16-packed)

#define NW_DW (IC * OC * 64)          // 737280 dwords: W as f16 n-pairs
#define NU_DW (NB * IC * 4)           // 1179648 dwords: u as f16 n-pairs
#define WS_NEED ((size_t)(NW_DW + NU_DW) * 4)
#define NWT (NW_DW / 4)               // 184320 W-convert threads (4 dw each)
#define NUT (NU_DW / 2)               // 589824 u-convert threads (2 dw each)

typedef float v2f __attribute__((ext_vector_type(2)));
typedef _Float16 h2 __attribute__((ext_vector_type(2)));

#if defined(__has_builtin)
#if __has_builtin(__builtin_amdgcn_fdot2)
#define HAVE_FDOT2 1
#endif
#endif

__device__ __forceinline__ float fdot2f(unsigned w, unsigned uu, float c) {
    h2 a = *(h2*)&w, b = *(h2*)&uu;
#ifdef HAVE_FDOT2
    return __builtin_amdgcn_fdot2(a, b, c, false);
#else
    return c + (float)a.x * (float)b.x + (float)a.y * (float)b.y;
#endif
}
__device__ __forceinline__ v2f h_v2(unsigned w) {
    h2 h = *(h2*)&w;
    v2f r = {(float)h.x, (float)h.y};
    return r;
}
__device__ __forceinline__ unsigned packh2(float a, float b) {
    h2 h = {(_Float16)a, (_Float16)b};
    return *(unsigned*)&h;
}
__device__ __forceinline__ unsigned h2u(h2 v) { return *(unsigned*)&v; }
__device__ __forceinline__ h2 u2h(unsigned v) { return *(h2*)&v; }
__device__ __forceinline__ h2 hshfl_xor(h2 v, int m) {
    unsigned b = *(unsigned*)&v;
    unsigned r = (unsigned)__shfl_xor((int)b, m, 64);
    return *(h2*)&r;
}

// ---- DPP reduce primitives (VALU pipe) ----
__device__ __forceinline__ float dpp_wave_max(float x) {
    int v = __float_as_int(x);
    int t;
#define MSTEP(ctrl) \
    t = __builtin_amdgcn_update_dpp(0xFF800000, v, (ctrl), 0xF, 0xF, false); \
    v = __float_as_int(fmaxf(__int_as_float(v), __int_as_float(t)));
    MSTEP(0x111) MSTEP(0x112) MSTEP(0x114) MSTEP(0x118) MSTEP(0x142) MSTEP(0x143)
#undef MSTEP
    return __int_as_float(__builtin_amdgcn_readlane(v, 63));
}
__device__ __forceinline__ float dpp_wave_sum(float x) {
    int v = __float_as_int(x);
    int t;
#define SSTEP(ctrl) \
    t = __builtin_amdgcn_update_dpp(0, v, (ctrl), 0xF, 0xF, false); \
    v = __float_as_int(__int_as_float(v) + __int_as_float(t));
    SSTEP(0x111) SSTEP(0x112) SSTEP(0x114) SSTEP(0x118) SSTEP(0x142) SSTEP(0x143)
#undef SSTEP
    return __int_as_float(__builtin_amdgcn_readlane(v, 63));
}
template<int CTRL> __device__ __forceinline__ float qadd(float x) {
    int t = __builtin_amdgcn_update_dpp(0, __float_as_int(x), CTRL, 0xF, 0xF, false);
    return x + __int_as_float(t);
}
template<int CTRL> __device__ __forceinline__ h2 hqadd(h2 v) {
    int t = __builtin_amdgcn_update_dpp(0, (int)h2u(v), CTRL, 0xF, 0xF, false);
    return v + u2h((unsigned)t);
}

// ---- Pre-pass (vectorized): W f32 -> f16 n-pairs (transposed layout);
//      u f32 -> f16 n-pairs. Layout identical to R17-R21:
// Wh dword e: k=e&3 (n-pair), mp=(e>>2)&3, q=(e>>4)&3, ij=e>>6; m=q*4+mp
//   value = pack(W[ij][2k][m], W[ij][2k+1][m])
// uh dword e: pr=e&3, bi=e>>2; value = pack(u[bi][2pr], u[bi][2pr+1])
__global__ void convert_kernel(const float* __restrict__ u,
                               const float* __restrict__ W,
                               unsigned* __restrict__ ws, int do_u) {
    const int tid = blockIdx.x * blockDim.x + threadIdx.x;
    if (tid < NWT) {
        // thread -> (ij, q, k); produces mp = 0..3
        const int k = tid & 3, q = (tid >> 2) & 3, ij = tid >> 4;
        const float* base = W + ((size_t)ij << 7) + (k << 5) + (q << 2);
        const float4 A = *(const float4*)base;        // W[ij][2k][q*4 .. +3]
        const float4 B = *(const float4*)(base + 16); // W[ij][2k+1][q*4 .. +3]
        unsigned* o = ws + ij * 64 + q * 16 + k;
        o[0]  = packh2(A.x, B.x);
        o[4]  = packh2(A.y, B.y);
        o[8]  = packh2(A.z, B.z);
        o[12] = packh2(A.w, B.w);
    } else if (do_u) {
        const int e = tid - NWT;
        if (e < NUT) {
            const float4 a = *(const float4*)(u + ((size_t)e << 2));
            *(uint2*)(ws + NW_DW + (e << 1)) =
                make_uint2(packh2(a.x, a.y), packh2(a.z, a.w));
        }
    }
}

template<bool UF16>
__global__ __launch_bounds__(1024, 8)
void caps_route_kernel(const float* __restrict__ u,
                       const unsigned* __restrict__ Wh,
                       const unsigned* __restrict__ ug,
                       float* __restrict__ out) {
    extern __shared__ unsigned smem_u[];
    unsigned* uh   = smem_u;                 // 2 tiles (73728 B)
    unsigned* r0p  = uh + 2 * TILE_DW;       // [2 bt][16 wid][8 dw] f16 (1024 B)
    unsigned* spart = r0p + 256;             // [2 par][part 128 | expM,se 32] (1280 B)

    const int t    = threadIdx.x;
    const int bx   = blockIdx.x;
    const int lane = t & 63;
    const int wid  = t >> 6;

    // XCD-aware (j, batch-pair) mapping (xcd = bx & 7 heuristic).
    int x = bx & 7, sg = bx >> 3;
    int j, p;
    if (sg < 128) { j = x; p = sg; }
    else { int s2v = sg - 128; j = 8 + (x >> 2); p = ((x & 3) << 5) + s2v; }
    const int bb = p * 2;  // batches bb, bb+1

    // ---- Phase A: uhat -> LDS f16 (half-XOR swizzle) + r0 column sums ----
    // (R18-proven structure; pairwise W loads keep the 32-VGPR wall.)
    {
        const int q  = t & 3;
        const int i0 = t >> 2;           // 0..255
        const int pb = (((q >> 1) ^ ((i0 >> 2) & 1)) << 2) + ((q & 1) << 1);
        const float* u0p = u + (size_t)bb * (IC * 8);
        const uint4* ua4 = (const uint4*)ug + (size_t)bb * IC;
        const uint4* ub4 = ua4 + IC;

        h2 sA01 = u2h(0u), sA23 = u2h(0u);
        h2 sB01 = u2h(0u), sB23 = u2h(0u);

        auto stage = [&](int i) {
            const uint4* wq4 = (const uint4*)Wh + (((size_t)(i * OC + j) << 2) + q) * 4;
            uint4 Ua, Ub;
            if constexpr (UF16) {
                Ua = ua4[i];
                Ub = ub4[i];
            } else {
                const float4 a0 = *(const float4*)(u0p + i * 8);
                const float4 a1 = *(const float4*)(u0p + i * 8 + 4);
                const float4 b0 = *(const float4*)(u0p + IC * 8 + i * 8);
                const float4 b1 = *(const float4*)(u0p + IC * 8 + i * 8 + 4);
                Ua = make_uint4(packh2(a0.x, a0.y), packh2(a0.z, a0.w),
                                packh2(a1.x, a1.y), packh2(a1.z, a1.w));
                Ub = make_uint4(packh2(b0.x, b0.y), packh2(b0.z, b0.w),
                                packh2(b1.x, b1.y), packh2(b1.z, b1.w));
            }
#define DOT8(acc, wm, Um) \
            acc = fdot2f(wm.x, Um.x, 0.f);  acc = fdot2f(wm.y, Um.y, acc); \
            acc = fdot2f(wm.z, Um.z, acc);  acc = fdot2f(wm.w, Um.w, acc);
            const uint4 w0 = wq4[0], w1 = wq4[1];
            float A0, A1, B0, B1;
            DOT8(A0, w0, Ua) DOT8(A1, w1, Ua)
            DOT8(B0, w0, Ub) DOT8(B1, w1, Ub)
            const unsigned pa01 = packh2(A0, A1), pb01 = packh2(B0, B1);
            const uint4 w2 = wq4[2], w3 = wq4[3];
            float A2, A3, B2, B3;
            DOT8(A2, w2, Ua) DOT8(A3, w3, Ua)
            DOT8(B2, w2, Ub) DOT8(B3, w3, Ub)
            const unsigned pa23 = packh2(A2, A3), pb23 = packh2(B2, B3);
#undef DOT8
            sA01 += u2h(pa01);  sA23 += u2h(pa23);
            sB01 += u2h(pb01);  sB23 += u2h(pb23);
            const int dst = (i << 3) + pb;
            *(uint2*)&uh[dst]           = make_uint2(pa01, pa23);
            *(uint2*)&uh[TILE_DW + dst] = make_uint2(pb01, pb23);
        };
#pragma unroll
        for (int k = 0; k < 4; ++k) stage(i0 + 256 * k);
        if (i0 < IC - 1024) stage(i0 + 1024);

#pragma unroll
        for (int o = 4; o <= 32; o <<= 1) {
            sA01 += hshfl_xor(sA01, o);  sA23 += hshfl_xor(sA23, o);
            sB01 += hshfl_xor(sB01, o);  sB23 += hshfl_xor(sB23, o);
        }
        if (lane < 4) {   // lane == q here
            *(uint2*)&r0p[wid * 8 + (lane << 1)]       = make_uint2(h2u(sA01), h2u(sA23));
            *(uint2*)&r0p[128 + wid * 8 + (lane << 1)] = make_uint2(h2u(sB01), h2u(sB23));
        }
    }

    __syncthreads();  // B0: uhat + r0 partials ready

    // ---- Routing: octet w8 of batch bt owns rows [w8*144, +144) ----
    const int bt = wid >> 3;
    const int w8 = wid & 7;
    const int rowbase = w8 * 144;          // bit2 of rowbase == 0 -> eB math valid
    const unsigned* uhT = uh + bt * TILE_DW;

    const int cp = lane & 7;               // m-pair this lane combines/stores
    const int i1 = rowbase + lane, i2 = i1 + 64, i3 = rowbase + 128 + lane;

    float L0 = 0.f, L1 = 0.f, L2 = (lane < 16) ? 0.f : -1e30f;

    for (int r = 0; r < 3; ++r) {
        if (r == 2 && w8 != 0) break;      // only w8==0 produces output

        // ---- combine -> s -> squash -> v (per-lane m-pair cp) ----
        float sx, sy;
        {
            v2f s2 = {0.f, 0.f};
            float inv;
            if (r == 0) {
                h2 a2 = u2h(0u);
#pragma unroll
                for (int w = 0; w < 16; ++w)
                    a2 += u2h(r0p[bt * 128 + w * 8 + cp]);
                s2.x = (float)a2.x; s2.y = (float)a2.y;
                inv = 1.0f / (float)IC;
            } else {
                const int base = ((r - 1) & 1) * 160;
                float ses = 0.f;
#pragma unroll
                for (int w = 0; w < 8; ++w) {
                    const unsigned pw = spart[base + bt * 64 + w * 8 + cp];
                    const float2 mse = *(const float2*)&spart[base + 128 + (bt * 8 + w) * 2];
                    const float fac = mse.x;           // e^{M_w} precomputed at store
                    const v2f pv = h_v2(pw);
                    s2.x += pv.x * fac;  s2.y += pv.y * fac;
                    ses += mse.y * fac;
                }
                inv = 1.0f / ses;
            }
            sx = s2.x * inv;  sy = s2.y * inv;
        }
        float p2 = sx * sx + sy * sy;
        p2 = qadd<0xB1>(p2);               // xor1 (quad_perm, VALU)
        p2 = qadd<0x4E>(p2);               // xor2
        p2 += __int_as_float(__builtin_amdgcn_ds_swizzle(__float_as_int(p2), 0x101F)); // xor4
        const float sc = p2 / ((1.0f + p2) * sqrtf(p2 + 1e-8f));
        const float vx = sx * sc, vy = sy * sc;

        if (r == 2) {
            if (lane < 8)
                *(float2*)&out[((size_t)(bb + bt) * OC + j) * 16 + (cp << 1)] =
                    make_float2(vx, vy);
            break;
        }

        // ---- broadcast v into position space: compile-time ds_swizzle ----
        const int pki = (int)packh2(vx, vy);
        unsigned vh[8];
        vh[0] = (unsigned)__builtin_amdgcn_ds_swizzle(pki, 0x001C);
        vh[1] = (unsigned)__builtin_amdgcn_ds_swizzle(pki, 0x003C);
        vh[2] = (unsigned)__builtin_amdgcn_ds_swizzle(pki, 0x005C);
        vh[3] = (unsigned)__builtin_amdgcn_ds_swizzle(pki, 0x007C);
        vh[4] = (unsigned)__builtin_amdgcn_ds_swizzle(pki, 0x101C);
        vh[5] = (unsigned)__builtin_amdgcn_ds_swizzle(pki, 0x103C);
        vh[6] = (unsigned)__builtin_amdgcn_ds_swizzle(pki, 0x105C);
        vh[7] = (unsigned)__builtin_amdgcn_ds_swizzle(pki, 0x107C);

        // ---- pass1: dp -> L ----
#define DP8(Lk, ii) { \
        const uint4 da = *(const uint4*)&uhT[(ii) << 3]; \
        const uint4 db = *(const uint4*)&uhT[((ii) << 3) + 4]; \
        float d1 = fdot2f(da.x, vh[0], 0.f); d1 = fdot2f(da.y, vh[1], d1); \
        d1 = fdot2f(da.z, vh[2], d1); d1 = fdot2f(da.w, vh[3], d1); \
        float d2 = fdot2f(db.x, vh[4], 0.f); d2 = fdot2f(db.y, vh[5], d2); \
        d2 = fdot2f(db.z, vh[6], d2); d2 = fdot2f(db.w, vh[7], d2); \
        (Lk) += d1 + d2; }
        DP8(L0, i1)
        DP8(L1, i2)
        if (lane < 16) { DP8(L2, i3) }
#undef DP8

        // ---- wave max via DPP ladder (range guard for f16 partials) ----
        const float M = dpp_wave_max(fmaxf(L0, fmaxf(L1, L2)));

        // ---- pass2: ev = exp(L-M); se; s-partials via v_pk_fma_f16 ----
        h2 sa[8];
#pragma unroll
        for (int k = 0; k < 8; ++k) sa[k] = u2h(0u);
        float sel = 0.f;
#define ROW2(Lk, ii) { \
        const uint4 da = *(const uint4*)&uhT[(ii) << 3]; \
        const uint4 db = *(const uint4*)&uhT[((ii) << 3) + 4]; \
        const float ev = __expf((Lk) - M); \
        sel += ev; \
        const h2 eh = u2h(packh2(ev, ev)); \
        sa[0] += u2h(da.x) * eh;  sa[1] += u2h(da.y) * eh; \
        sa[2] += u2h(da.z) * eh;  sa[3] += u2h(da.w) * eh; \
        sa[4] += u2h(db.x) * eh;  sa[5] += u2h(db.y) * eh; \
        sa[6] += u2h(db.z) * eh;  sa[7] += u2h(db.w) * eh; }
        ROW2(L0, i1)
        ROW2(L1, i2)
        if (lane < 16) { ROW2(L2, i3) }
#undef ROW2
        const float se = dpp_wave_sum(sel);

        // ---- narrowing XOR tree; step1 selects on (lane5 ^ eB) => m-space ----
        h2 tt;
        {
            const int eB = (lane >> 2) & 1;
            const bool s5 = (((lane >> 5) & 1) ^ eB) != 0;
            const bool b4 = (lane & 16) != 0, b3 = (lane & 8) != 0;
            h2 tq[4];
#pragma unroll
            for (int q = 0; q < 4; ++q) {
                h2 snd = s5 ? sa[q] : sa[q + 4];
                tq[q] = (s5 ? sa[q + 4] : sa[q]) + hshfl_xor(snd, 32);
            }
            h2 uq[2];
#pragma unroll
            for (int q = 0; q < 2; ++q) {
                h2 snd = b4 ? tq[q] : tq[q + 2];
                uq[q] = (b4 ? tq[q + 2] : tq[q]) + hshfl_xor(snd, 16);
            }
            {
                h2 snd = b3 ? uq[0] : uq[1];
                tt = (b3 ? uq[1] : uq[0]) + hshfl_xor(snd, 8);
            }
            tt += u2h((unsigned)__builtin_amdgcn_ds_swizzle((int)h2u(tt), 0x101F)); // xor4
            tt = hqadd<0x4E>(tt);          // xor2 (quad_perm)
            tt = hqadd<0xB1>(tt);          // xor1
        }

        // ---- store partials: part[bt][w8][p] + (e^M, se)[bt][w8] ----
        const int po = (r & 1) * 160;
        if ((lane & 7) == 0)
            spart[po + bt * 64 + w8 * 8 + (lane >> 3)] = h2u(tt);
        if (lane == 1)
            *(float2*)&spart[po + 128 + (bt * 8 + w8) * 2] = make_float2(__expf(M), se);
        __syncthreads();  // B(r+1)
    }
}

extern "C" void kernel_launch(void* const* d_in, const int* in_sizes, int n_in,
                              void* d_out, int out_size, void* d_ws, size_t ws_size,
                              hipStream_t stream) {
    const float* u = (const float*)d_in[0];
    const float* W = (const float*)d_in[1];
    float* out = (float*)d_out;
    unsigned* ws = (unsigned*)d_ws;

    const int do_u = (ws_size >= WS_NEED) ? 1 : 0;
    const int total = NWT + (do_u ? NUT : 0);
    convert_kernel<<<(total + 255) / 256, 256, 0, stream>>>(u, W, ws, do_u);

    const size_t shmem = (size_t)(2 * TILE_DW + 256 + 320) * 4;  // 76032 B
    if (do_u) {
        hipFuncSetAttribute((const void*)caps_route_kernel<true>,
                            hipFuncAttributeMaxDynamicSharedMemorySize, (int)shmem);
        caps_route_kernel<true><<<(NB / 2) * OC, 1024, shmem, stream>>>(u, ws, ws + NW_DW, out);
    } else {
        hipFuncSetAttribute((const void*)caps_route_kernel<false>,
                            hipFuncAttributeMaxDynamicSharedMemorySize, (int)shmem);
        caps_route_kernel<false><<<(NB / 2) * OC, 1024, shmem, stream>>>(u, ws, ws + NW_DW, out);
    }
}

// Round 8
// 103.697 us; speedup vs baseline: 1.2003x; 1.0313x over previous
//
#include <hip/hip_runtime.h>
#include <hip/hip_bf16.h>
#include <math.h>

// CapsNet dynamic routing. R24 = R23 + p-major XCD mapping + transposed
// partial layouts (vector combine reads).
// R23 post-mortem: convert-gap theory dead (fixed 2nd-launch overhead, not
// memory). Main kernel levers:
//  (1) FETCH 22.2MB/dispatch @480GB/s ~= the whole 46us. Ideal cold = 7.7MB
//      (W-f16 2.95 + u-f16 4.7). Extra ~14MB = u re-fetch per XCD: j-major
//      mapping streams ALL 128 pairs through every XCD (4.7MB > L2 slack).
//      p-major: j=g/16, p=(g%16)*8+x -> XCD x sees only p===x (mod 8):
//      footprint = W 2.95MB + u 0.59MB = 3.5MB < 4MB L2. Bijective.
//  (2) post-barrier combine burst: 32 waves x 16 scalar LDS reads. Transpose
//      spart/r0p to [bt][cp][w] -> combine reads 2-6 b128s (r0: 16->4).
//      Two-half loads keep VGPR <= 32.
// Math bit-identical (same sum order) -> absmax 0.00390625 exactly.
// Tripwires: VGPR == 32, WRITE_SIZE ~160KB, FETCH <= 14MB (else xcd!=bx&7
// assumption wrong -> retract mapping theory).
//
// u: [256][1152][8] f32; weight: [1152][10][8][16] f32; out: [256][10][16] f32

#define IC 1152
#define OC 10
#define NB 256
#define TILE_DW (IC * 8)              // dwords per batch tile (f16-packed)

#define NW_DW (IC * OC * 64)          // 737280 dwords: W as f16 n-pairs
#define NU_DW (NB * IC * 4)           // 1179648 dwords: u as f16 n-pairs
#define WS_NEED ((size_t)(NW_DW + NU_DW) * 4)
#define NWT (NW_DW / 4)               // 184320 W-convert threads (4 dw each)
#define NUT (NU_DW / 2)               // 589824 u-convert threads (2 dw each)

typedef float v2f __attribute__((ext_vector_type(2)));
typedef _Float16 h2 __attribute__((ext_vector_type(2)));

#if defined(__has_builtin)
#if __has_builtin(__builtin_amdgcn_fdot2)
#define HAVE_FDOT2 1
#endif
#endif

__device__ __forceinline__ float fdot2f(unsigned w, unsigned uu, float c) {
    h2 a = *(h2*)&w, b = *(h2*)&uu;
#ifdef HAVE_FDOT2
    return __builtin_amdgcn_fdot2(a, b, c, false);
#else
    return c + (float)a.x * (float)b.x + (float)a.y * (float)b.y;
#endif
}
__device__ __forceinline__ v2f h_v2(unsigned w) {
    h2 h = *(h2*)&w;
    v2f r = {(float)h.x, (float)h.y};
    return r;
}
__device__ __forceinline__ unsigned packh2(float a, float b) {
    h2 h = {(_Float16)a, (_Float16)b};
    return *(unsigned*)&h;
}
__device__ __forceinline__ unsigned h2u(h2 v) { return *(unsigned*)&v; }
__device__ __forceinline__ h2 u2h(unsigned v) { return *(h2*)&v; }
__device__ __forceinline__ h2 hshfl_xor(h2 v, int m) {
    unsigned b = *(unsigned*)&v;
    unsigned r = (unsigned)__shfl_xor((int)b, m, 64);
    return *(h2*)&r;
}

// ---- DPP reduce primitives (VALU pipe) ----
__device__ __forceinline__ float dpp_wave_max(float x) {
    int v = __float_as_int(x);
    int t;
#define MSTEP(ctrl) \
    t = __builtin_amdgcn_update_dpp(0xFF800000, v, (ctrl), 0xF, 0xF, false); \
    v = __float_as_int(fmaxf(__int_as_float(v), __int_as_float(t)));
    MSTEP(0x111) MSTEP(0x112) MSTEP(0x114) MSTEP(0x118) MSTEP(0x142) MSTEP(0x143)
#undef MSTEP
    return __int_as_float(__builtin_amdgcn_readlane(v, 63));
}
__device__ __forceinline__ float dpp_wave_sum(float x) {
    int v = __float_as_int(x);
    int t;
#define SSTEP(ctrl) \
    t = __builtin_amdgcn_update_dpp(0, v, (ctrl), 0xF, 0xF, false); \
    v = __float_as_int(__int_as_float(v) + __int_as_float(t));
    SSTEP(0x111) SSTEP(0x112) SSTEP(0x114) SSTEP(0x118) SSTEP(0x142) SSTEP(0x143)
#undef SSTEP
    return __int_as_float(__builtin_amdgcn_readlane(v, 63));
}
template<int CTRL> __device__ __forceinline__ float qadd(float x) {
    int t = __builtin_amdgcn_update_dpp(0, __float_as_int(x), CTRL, 0xF, 0xF, false);
    return x + __int_as_float(t);
}
template<int CTRL> __device__ __forceinline__ h2 hqadd(h2 v) {
    int t = __builtin_amdgcn_update_dpp(0, (int)h2u(v), CTRL, 0xF, 0xF, false);
    return v + u2h((unsigned)t);
}

// ---- Pre-pass (vectorized, R23): W f32 -> f16 n-pairs; u f32 -> f16 pairs ----
__global__ void convert_kernel(const float* __restrict__ u,
                               const float* __restrict__ W,
                               unsigned* __restrict__ ws, int do_u) {
    const int tid = blockIdx.x * blockDim.x + threadIdx.x;
    if (tid < NWT) {
        const int k = tid & 3, q = (tid >> 2) & 3, ij = tid >> 4;
        const float* base = W + ((size_t)ij << 7) + (k << 5) + (q << 2);
        const float4 A = *(const float4*)base;        // W[ij][2k][q*4 .. +3]
        const float4 B = *(const float4*)(base + 16); // W[ij][2k+1][q*4 .. +3]
        unsigned* o = ws + ij * 64 + q * 16 + k;
        o[0]  = packh2(A.x, B.x);
        o[4]  = packh2(A.y, B.y);
        o[8]  = packh2(A.z, B.z);
        o[12] = packh2(A.w, B.w);
    } else if (do_u) {
        const int e = tid - NWT;
        if (e < NUT) {
            const float4 a = *(const float4*)(u + ((size_t)e << 2));
            *(uint2*)(ws + NW_DW + (e << 1)) =
                make_uint2(packh2(a.x, a.y), packh2(a.z, a.w));
        }
    }
}

template<bool UF16>
__global__ __launch_bounds__(1024, 8)
void caps_route_kernel(const float* __restrict__ u,
                       const unsigned* __restrict__ Wh,
                       const unsigned* __restrict__ ug,
                       float* __restrict__ out) {
    extern __shared__ unsigned smem_u[];
    unsigned* uh   = smem_u;                 // 2 tiles (73728 B)
    unsigned* r0p  = uh + 2 * TILE_DW;       // [2 bt][8 cp][16 w] f16 (1024 B)
    unsigned* spart = r0p + 256;             // [2 par][[bt][cp][w8] 128 | expM,se 32]

    const int t    = threadIdx.x;
    const int bx   = blockIdx.x;
    const int lane = t & 63;
    const int wid  = t >> 6;

    // p-major XCD mapping (xcd = bx & 7 heuristic): XCD x gets p === x (mod 8)
    // -> per-XCD L2 footprint = full W (2.95MB) + u slice (0.59MB) < 4MB.
    const int x = bx & 7, g = bx >> 3;       // g in [0,160)
    const int j = g >> 4;                    // g/16: 0..9
    const int p = ((g & 15) << 3) + x;       // 0..127, p%8 == x
    const int bb = p * 2;                    // batches bb, bb+1

    // ---- Phase A: uhat -> LDS f16 (half-XOR swizzle) + r0 column sums ----
    // (R18-proven structure; pairwise W loads keep the 32-VGPR wall.)
    {
        const int q  = t & 3;
        const int i0 = t >> 2;           // 0..255
        const int pb = (((q >> 1) ^ ((i0 >> 2) & 1)) << 2) + ((q & 1) << 1);
        const float* u0p = u + (size_t)bb * (IC * 8);
        const uint4* ua4 = (const uint4*)ug + (size_t)bb * IC;
        const uint4* ub4 = ua4 + IC;

        h2 sA01 = u2h(0u), sA23 = u2h(0u);
        h2 sB01 = u2h(0u), sB23 = u2h(0u);

        auto stage = [&](int i) {
            const uint4* wq4 = (const uint4*)Wh + (((size_t)(i * OC + j) << 2) + q) * 4;
            uint4 Ua, Ub;
            if constexpr (UF16) {
                Ua = ua4[i];
                Ub = ub4[i];
            } else {
                const float4 a0 = *(const float4*)(u0p + i * 8);
                const float4 a1 = *(const float4*)(u0p + i * 8 + 4);
                const float4 b0 = *(const float4*)(u0p + IC * 8 + i * 8);
                const float4 b1 = *(const float4*)(u0p + IC * 8 + i * 8 + 4);
                Ua = make_uint4(packh2(a0.x, a0.y), packh2(a0.z, a0.w),
                                packh2(a1.x, a1.y), packh2(a1.z, a1.w));
                Ub = make_uint4(packh2(b0.x, b0.y), packh2(b0.z, b0.w),
                                packh2(b1.x, b1.y), packh2(b1.z, b1.w));
            }
#define DOT8(acc, wm, Um) \
            acc = fdot2f(wm.x, Um.x, 0.f);  acc = fdot2f(wm.y, Um.y, acc); \
            acc = fdot2f(wm.z, Um.z, acc);  acc = fdot2f(wm.w, Um.w, acc);
            const uint4 w0 = wq4[0], w1 = wq4[1];
            float A0, A1, B0, B1;
            DOT8(A0, w0, Ua) DOT8(A1, w1, Ua)
            DOT8(B0, w0, Ub) DOT8(B1, w1, Ub)
            const unsigned pa01 = packh2(A0, A1), pb01 = packh2(B0, B1);
            const uint4 w2 = wq4[2], w3 = wq4[3];
            float A2, A3, B2, B3;
            DOT8(A2, w2, Ua) DOT8(A3, w3, Ua)
            DOT8(B2, w2, Ub) DOT8(B3, w3, Ub)
            const unsigned pa23 = packh2(A2, A3), pb23 = packh2(B2, B3);
#undef DOT8
            sA01 += u2h(pa01);  sA23 += u2h(pa23);
            sB01 += u2h(pb01);  sB23 += u2h(pb23);
            const int dst = (i << 3) + pb;
            *(uint2*)&uh[dst]           = make_uint2(pa01, pa23);
            *(uint2*)&uh[TILE_DW + dst] = make_uint2(pb01, pb23);
        };
#pragma unroll
        for (int k = 0; k < 4; ++k) stage(i0 + 256 * k);
        if (i0 < IC - 1024) stage(i0 + 1024);

#pragma unroll
        for (int o = 4; o <= 32; o <<= 1) {
            sA01 += hshfl_xor(sA01, o);  sA23 += hshfl_xor(sA23, o);
            sB01 += hshfl_xor(sB01, o);  sB23 += hshfl_xor(sB23, o);
        }
        if (lane < 4) {   // lane == q here; cp pairs 2q (A01/B01), 2q+1 (A23/B23)
            const int c0 = lane << 1;
            r0p[c0 * 16 + wid]             = h2u(sA01);
            r0p[(c0 + 1) * 16 + wid]       = h2u(sA23);
            r0p[128 + c0 * 16 + wid]       = h2u(sB01);
            r0p[128 + (c0 + 1) * 16 + wid] = h2u(sB23);
        }
    }

    __syncthreads();  // B0: uhat + r0 partials ready

    // ---- Routing: octet w8 of batch bt owns rows [w8*144, +144) ----
    const int bt = wid >> 3;
    const int w8 = wid & 7;
    const int rowbase = w8 * 144;          // bit2 of rowbase == 0 -> eB math valid
    const unsigned* uhT = uh + bt * TILE_DW;

    const int cp = lane & 7;               // m-pair this lane combines/stores
    const int i1 = rowbase + lane, i2 = i1 + 64, i3 = rowbase + 128 + lane;

    float L0 = 0.f, L1 = 0.f, L2 = (lane < 16) ? 0.f : -1e30f;

    for (int r = 0; r < 3; ++r) {
        if (r == 2 && w8 != 0) break;      // only w8==0 produces output

        // ---- combine -> s -> squash -> v (per-lane m-pair cp) ----
        float sx, sy;
        {
            v2f s2 = {0.f, 0.f};
            float inv;
            if (r == 0) {
                // r0p[bt][cp][w16]: 4 x b128, two halves (VGPR guard)
                const unsigned* rp = &r0p[bt * 128 + cp * 16];
                h2 a2 = u2h(0u);
                {
                    const uint4 v0 = *(const uint4*)&rp[0];
                    const uint4 v1 = *(const uint4*)&rp[4];
                    a2 += u2h(v0.x) + u2h(v0.y) + u2h(v0.z) + u2h(v0.w);
                    a2 += u2h(v1.x) + u2h(v1.y) + u2h(v1.z) + u2h(v1.w);
                }
                {
                    const uint4 v2 = *(const uint4*)&rp[8];
                    const uint4 v3 = *(const uint4*)&rp[12];
                    a2 += u2h(v2.x) + u2h(v2.y) + u2h(v2.z) + u2h(v2.w);
                    a2 += u2h(v3.x) + u2h(v3.y) + u2h(v3.z) + u2h(v3.w);
                }
                s2.x = (float)a2.x; s2.y = (float)a2.y;
                inv = 1.0f / (float)IC;
            } else {
                const int base = ((r - 1) & 1) * 160;
                const unsigned* pp = &spart[base + bt * 64 + cp * 8];
                const unsigned* ee = &spart[base + 128 + bt * 16];
                float ses = 0.f;
#define CW(pw, fm, fs) { \
                const float fac = __uint_as_float(fm); \
                const v2f pv = h_v2(pw); \
                s2.x += pv.x * fac;  s2.y += pv.y * fac; \
                ses += __uint_as_float(fs) * fac; }
                {   // half 1: w = 0..3
                    const uint4 P0 = *(const uint4*)&pp[0];
                    const uint4 E0 = *(const uint4*)&ee[0];
                    const uint4 E1 = *(const uint4*)&ee[4];
                    CW(P0.x, E0.x, E0.y) CW(P0.y, E0.z, E0.w)
                    CW(P0.z, E1.x, E1.y) CW(P0.w, E1.z, E1.w)
                }
                {   // half 2: w = 4..7
                    const uint4 P1 = *(const uint4*)&pp[4];
                    const uint4 E2 = *(const uint4*)&ee[8];
                    const uint4 E3 = *(const uint4*)&ee[12];
                    CW(P1.x, E2.x, E2.y) CW(P1.y, E2.z, E2.w)
                    CW(P1.z, E3.x, E3.y) CW(P1.w, E3.z, E3.w)
                }
#undef CW
                inv = 1.0f / ses;
            }
            sx = s2.x * inv;  sy = s2.y * inv;
        }
        float p2 = sx * sx + sy * sy;
        p2 = qadd<0xB1>(p2);               // xor1 (quad_perm, VALU)
        p2 = qadd<0x4E>(p2);               // xor2
        p2 += __int_as_float(__builtin_amdgcn_ds_swizzle(__float_as_int(p2), 0x101F)); // xor4
        const float sc = p2 / ((1.0f + p2) * sqrtf(p2 + 1e-8f));
        const float vx = sx * sc, vy = sy * sc;

        if (r == 2) {
            if (lane < 8)
                *(float2*)&out[((size_t)(bb + bt) * OC + j) * 16 + (cp << 1)] =
                    make_float2(vx, vy);
            break;
        }

        // ---- broadcast v into position space: compile-time ds_swizzle ----
        const int pki = (int)packh2(vx, vy);
        unsigned vh[8];
        vh[0] = (unsigned)__builtin_amdgcn_ds_swizzle(pki, 0x001C);
        vh[1] = (unsigned)__builtin_amdgcn_ds_swizzle(pki, 0x003C);
        vh[2] = (unsigned)__builtin_amdgcn_ds_swizzle(pki, 0x005C);
        vh[3] = (unsigned)__builtin_amdgcn_ds_swizzle(pki, 0x007C);
        vh[4] = (unsigned)__builtin_amdgcn_ds_swizzle(pki, 0x101C);
        vh[5] = (unsigned)__builtin_amdgcn_ds_swizzle(pki, 0x103C);
        vh[6] = (unsigned)__builtin_amdgcn_ds_swizzle(pki, 0x105C);
        vh[7] = (unsigned)__builtin_amdgcn_ds_swizzle(pki, 0x107C);

        // ---- pass1: dp -> L ----
#define DP8(Lk, ii) { \
        const uint4 da = *(const uint4*)&uhT[(ii) << 3]; \
        const uint4 db = *(const uint4*)&uhT[((ii) << 3) + 4]; \
        float d1 = fdot2f(da.x, vh[0], 0.f); d1 = fdot2f(da.y, vh[1], d1); \
        d1 = fdot2f(da.z, vh[2], d1); d1 = fdot2f(da.w, vh[3], d1); \
        float d2 = fdot2f(db.x, vh[4], 0.f); d2 = fdot2f(db.y, vh[5], d2); \
        d2 = fdot2f(db.z, vh[6], d2); d2 = fdot2f(db.w, vh[7], d2); \
        (Lk) += d1 + d2; }
        DP8(L0, i1)
        DP8(L1, i2)
        if (lane < 16) { DP8(L2, i3) }
#undef DP8

        // ---- wave max via DPP ladder (range guard for f16 partials) ----
        const float M = dpp_wave_max(fmaxf(L0, fmaxf(L1, L2)));

        // ---- pass2: ev = exp(L-M); se; s-partials via v_pk_fma_f16 ----
        h2 sa[8];
#pragma unroll
        for (int k = 0; k < 8; ++k) sa[k] = u2h(0u);
        float sel = 0.f;
#define ROW2(Lk, ii) { \
        const uint4 da = *(const uint4*)&uhT[(ii) << 3]; \
        const uint4 db = *(const uint4*)&uhT[((ii) << 3) + 4]; \
        const float ev = __expf((Lk) - M); \
        sel += ev; \
        const h2 eh = u2h(packh2(ev, ev)); \
        sa[0] += u2h(da.x) * eh;  sa[1] += u2h(da.y) * eh; \
        sa[2] += u2h(da.z) * eh;  sa[3] += u2h(da.w) * eh; \
        sa[4] += u2h(db.x) * eh;  sa[5] += u2h(db.y) * eh; \
        sa[6] += u2h(db.z) * eh;  sa[7] += u2h(db.w) * eh; }
        ROW2(L0, i1)
        ROW2(L1, i2)
        if (lane < 16) { ROW2(L2, i3) }
#undef ROW2
        const float se = dpp_wave_sum(sel);

        // ---- narrowing XOR tree; step1 selects on (lane5 ^ eB) => m-space ----
        h2 tt;
        {
            const int eB = (lane >> 2) & 1;
            const bool s5 = (((lane >> 5) & 1) ^ eB) != 0;
            const bool b4 = (lane & 16) != 0, b3 = (lane & 8) != 0;
            h2 tq[4];
#pragma unroll
            for (int q = 0; q < 4; ++q) {
                h2 snd = s5 ? sa[q] : sa[q + 4];
                tq[q] = (s5 ? sa[q + 4] : sa[q]) + hshfl_xor(snd, 32);
            }
            h2 uq[2];
#pragma unroll
            for (int q = 0; q < 2; ++q) {
                h2 snd = b4 ? tq[q] : tq[q + 2];
                uq[q] = (b4 ? tq[q + 2] : tq[q]) + hshfl_xor(snd, 16);
            }
            {
                h2 snd = b3 ? uq[0] : uq[1];
                tt = (b3 ? uq[1] : uq[0]) + hshfl_xor(snd, 8);
            }
            tt += u2h((unsigned)__builtin_amdgcn_ds_swizzle((int)h2u(tt), 0x101F)); // xor4
            tt = hqadd<0x4E>(tt);          // xor2 (quad_perm)
            tt = hqadd<0xB1>(tt);          // xor1
        }

        // ---- store partials transposed: [bt][cp][w8] + (e^M, se)[bt][w8] ----
        const int po = (r & 1) * 160;
        if ((lane & 7) == 0)
            spart[po + bt * 64 + (lane >> 3) * 8 + w8] = h2u(tt);
        if (lane == 1)
            *(float2*)&spart[po + 128 + (bt * 8 + w8) * 2] = make_float2(__expf(M), se);
        __syncthreads();  // B(r+1)
    }
}

extern "C" void kernel_launch(void* const* d_in, const int* in_sizes, int n_in,
                              void* d_out, int out_size, void* d_ws, size_t ws_size,
                              hipStream_t stream) {
    const float* u = (const float*)d_in[0];
    const float* W = (const float*)d_in[1];
    float* out = (float*)d_out;
    unsigned* ws = (unsigned*)d_ws;

    const int do_u = (ws_size >= WS_NEED) ? 1 : 0;
    const int total = NWT + (do_u ? NUT : 0);
    convert_kernel<<<(total + 255) / 256, 256, 0, stream>>>(u, W, ws, do_u);

    const size_t shmem = (size_t)(2 * TILE_DW + 256 + 320) * 4;  // 76032 B
    if (do_u) {
        hipFuncSetAttribute((const void*)caps_route_kernel<true>,
                            hipFuncAttributeMaxDynamicSharedMemorySize, (int)shmem);
        caps_route_kernel<true><<<(NB / 2) * OC, 1024, shmem, stream>>>(u, ws, ws + NW_DW, out);
    } else {
        hipFuncSetAttribute((const void*)caps_route_kernel<false>,
                            hipFuncAttributeMaxDynamicSharedMemorySize, (int)shmem);
        caps_route_kernel<false><<<(NB / 2) * OC, 1024, shmem, stream>>>(u, ws, ws + NW_DW, out);
    }
}

// Round 9
// 102.629 us; speedup vs baseline: 1.2128x; 1.0104x over previous
//
#include <hip/hip_runtime.h>
#include <hip/hip_bf16.h>
#include <math.h>

// CapsNet dynamic routing. R25 = R24 + padded partial strides + balanced rows.
// R24 post-mortem: p-major XCD mapping confirmed (FETCH 22.2->13.9MB, dur
// 46.2->43.6us) but transposed combine layouts doubled bank conflicts
// (655K->1.23M: stride-16 puts 16 b128s on 8 banks). R25:
//  (1) pad r0p cp-stride 16->20 dw, spart partial cp-stride 8->12 dw ->
//      bank bases {0,20,8,28,16,4,24,12} cover all 32 banks, 16B-aligned.
//  (2) balanced row partition: 1152 rows/batch = 18 full-wave passes;
//      waves 0-5 own 128 rows (2 passes), waves 6-7 own 192 (3 passes).
//      Kills the lane<16 quarter-idle tail pass: 24 -> 18 wave-passes/batch
//      (-25% row-loop issue), zero divergence (wave-uniform branch).
//      Partition-safe: per-wave M/se/tt partials sum over any row set;
//      all bases % 8 == 0 keeps eB parity math valid.
// LDS 76.8KB (x2 = 153.6 <= 160) -> still 2 blocks/CU.
// Tripwires: VGPR == 32, WRITE_SIZE ~160KB, conflicts <= ~0.65M,
// absmax <= 0.0059.
//
// u: [256][1152][8] f32; weight: [1152][10][8][16] f32; out: [256][10][16] f32

#define IC 1152
#define OC 10
#define NB 256
#define TILE_DW (IC * 8)              // dwords per batch tile (f16-packed)

#define NW_DW (IC * OC * 64)          // 737280 dwords: W as f16 n-pairs
#define NU_DW (NB * IC * 4)           // 1179648 dwords: u as f16 n-pairs
#define WS_NEED ((size_t)(NW_DW + NU_DW) * 4)
#define NWT (NW_DW / 4)               // 184320 W-convert threads (4 dw each)
#define NUT (NU_DW / 2)               // 589824 u-convert threads (2 dw each)

typedef float v2f __attribute__((ext_vector_type(2)));
typedef _Float16 h2 __attribute__((ext_vector_type(2)));

#if defined(__has_builtin)
#if __has_builtin(__builtin_amdgcn_fdot2)
#define HAVE_FDOT2 1
#endif
#endif

__device__ __forceinline__ float fdot2f(unsigned w, unsigned uu, float c) {
    h2 a = *(h2*)&w, b = *(h2*)&uu;
#ifdef HAVE_FDOT2
    return __builtin_amdgcn_fdot2(a, b, c, false);
#else
    return c + (float)a.x * (float)b.x + (float)a.y * (float)b.y;
#endif
}
__device__ __forceinline__ v2f h_v2(unsigned w) {
    h2 h = *(h2*)&w;
    v2f r = {(float)h.x, (float)h.y};
    return r;
}
__device__ __forceinline__ unsigned packh2(float a, float b) {
    h2 h = {(_Float16)a, (_Float16)b};
    return *(unsigned*)&h;
}
__device__ __forceinline__ unsigned h2u(h2 v) { return *(unsigned*)&v; }
__device__ __forceinline__ h2 u2h(unsigned v) { return *(h2*)&v; }
__device__ __forceinline__ h2 hshfl_xor(h2 v, int m) {
    unsigned b = *(unsigned*)&v;
    unsigned r = (unsigned)__shfl_xor((int)b, m, 64);
    return *(h2*)&r;
}

// ---- DPP reduce primitives (VALU pipe) ----
__device__ __forceinline__ float dpp_wave_max(float x) {
    int v = __float_as_int(x);
    int t;
#define MSTEP(ctrl) \
    t = __builtin_amdgcn_update_dpp(0xFF800000, v, (ctrl), 0xF, 0xF, false); \
    v = __float_as_int(fmaxf(__int_as_float(v), __int_as_float(t)));
    MSTEP(0x111) MSTEP(0x112) MSTEP(0x114) MSTEP(0x118) MSTEP(0x142) MSTEP(0x143)
#undef MSTEP
    return __int_as_float(__builtin_amdgcn_readlane(v, 63));
}
__device__ __forceinline__ float dpp_wave_sum(float x) {
    int v = __float_as_int(x);
    int t;
#define SSTEP(ctrl) \
    t = __builtin_amdgcn_update_dpp(0, v, (ctrl), 0xF, 0xF, false); \
    v = __float_as_int(__int_as_float(v) + __int_as_float(t));
    SSTEP(0x111) SSTEP(0x112) SSTEP(0x114) SSTEP(0x118) SSTEP(0x142) SSTEP(0x143)
#undef SSTEP
    return __int_as_float(__builtin_amdgcn_readlane(v, 63));
}
template<int CTRL> __device__ __forceinline__ float qadd(float x) {
    int t = __builtin_amdgcn_update_dpp(0, __float_as_int(x), CTRL, 0xF, 0xF, false);
    return x + __int_as_float(t);
}
template<int CTRL> __device__ __forceinline__ h2 hqadd(h2 v) {
    int t = __builtin_amdgcn_update_dpp(0, (int)h2u(v), CTRL, 0xF, 0xF, false);
    return v + u2h((unsigned)t);
}

// ---- Pre-pass (vectorized, R23): W f32 -> f16 n-pairs; u f32 -> f16 pairs ----
__global__ void convert_kernel(const float* __restrict__ u,
                               const float* __restrict__ W,
                               unsigned* __restrict__ ws, int do_u) {
    const int tid = blockIdx.x * blockDim.x + threadIdx.x;
    if (tid < NWT) {
        const int k = tid & 3, q = (tid >> 2) & 3, ij = tid >> 4;
        const float* base = W + ((size_t)ij << 7) + (k << 5) + (q << 2);
        const float4 A = *(const float4*)base;        // W[ij][2k][q*4 .. +3]
        const float4 B = *(const float4*)(base + 16); // W[ij][2k+1][q*4 .. +3]
        unsigned* o = ws + ij * 64 + q * 16 + k;
        o[0]  = packh2(A.x, B.x);
        o[4]  = packh2(A.y, B.y);
        o[8]  = packh2(A.z, B.z);
        o[12] = packh2(A.w, B.w);
    } else if (do_u) {
        const int e = tid - NWT;
        if (e < NUT) {
            const float4 a = *(const float4*)(u + ((size_t)e << 2));
            *(uint2*)(ws + NW_DW + (e << 1)) =
                make_uint2(packh2(a.x, a.y), packh2(a.z, a.w));
        }
    }
}

template<bool UF16>
__global__ __launch_bounds__(1024, 8)
void caps_route_kernel(const float* __restrict__ u,
                       const unsigned* __restrict__ Wh,
                       const unsigned* __restrict__ ug,
                       float* __restrict__ out) {
    extern __shared__ unsigned smem_u[];
    unsigned* uh   = smem_u;                 // 2 tiles (73728 B)
    unsigned* r0p  = uh + 2 * TILE_DW;       // [2 bt][8 cp][20 pad] f16 (1280 B)
    unsigned* spart = r0p + 320;             // [2 par][[bt][cp*12][w8] 192 | expM,se 32]

    const int t    = threadIdx.x;
    const int bx   = blockIdx.x;
    const int lane = t & 63;
    const int wid  = t >> 6;

    // p-major XCD mapping (xcd = bx & 7): XCD x gets p === x (mod 8)
    // -> per-XCD L2 footprint = full W (2.95MB) + u slice (0.59MB) < 4MB.
    const int x = bx & 7, g = bx >> 3;       // g in [0,160)
    const int j = g >> 4;                    // g/16: 0..9
    const int p = ((g & 15) << 3) + x;       // 0..127, p%8 == x
    const int bb = p * 2;                    // batches bb, bb+1

    // ---- Phase A: uhat -> LDS f16 (half-XOR swizzle) + r0 column sums ----
    {
        const int q  = t & 3;
        const int i0 = t >> 2;           // 0..255
        const int pb = (((q >> 1) ^ ((i0 >> 2) & 1)) << 2) + ((q & 1) << 1);
        const float* u0p = u + (size_t)bb * (IC * 8);
        const uint4* ua4 = (const uint4*)ug + (size_t)bb * IC;
        const uint4* ub4 = ua4 + IC;

        h2 sA01 = u2h(0u), sA23 = u2h(0u);
        h2 sB01 = u2h(0u), sB23 = u2h(0u);

        auto stage = [&](int i) {
            const uint4* wq4 = (const uint4*)Wh + (((size_t)(i * OC + j) << 2) + q) * 4;
            uint4 Ua, Ub;
            if constexpr (UF16) {
                Ua = ua4[i];
                Ub = ub4[i];
            } else {
                const float4 a0 = *(const float4*)(u0p + i * 8);
                const float4 a1 = *(const float4*)(u0p + i * 8 + 4);
                const float4 b0 = *(const float4*)(u0p + IC * 8 + i * 8);
                const float4 b1 = *(const float4*)(u0p + IC * 8 + i * 8 + 4);
                Ua = make_uint4(packh2(a0.x, a0.y), packh2(a0.z, a0.w),
                                packh2(a1.x, a1.y), packh2(a1.z, a1.w));
                Ub = make_uint4(packh2(b0.x, b0.y), packh2(b0.z, b0.w),
                                packh2(b1.x, b1.y), packh2(b1.z, b1.w));
            }
#define DOT8(acc, wm, Um) \
            acc = fdot2f(wm.x, Um.x, 0.f);  acc = fdot2f(wm.y, Um.y, acc); \
            acc = fdot2f(wm.z, Um.z, acc);  acc = fdot2f(wm.w, Um.w, acc);
            const uint4 w0 = wq4[0], w1 = wq4[1];
            float A0, A1, B0, B1;
            DOT8(A0, w0, Ua) DOT8(A1, w1, Ua)
            DOT8(B0, w0, Ub) DOT8(B1, w1, Ub)
            const unsigned pa01 = packh2(A0, A1), pb01 = packh2(B0, B1);
            const uint4 w2 = wq4[2], w3 = wq4[3];
            float A2, A3, B2, B3;
            DOT8(A2, w2, Ua) DOT8(A3, w3, Ua)
            DOT8(B2, w2, Ub) DOT8(B3, w3, Ub)
            const unsigned pa23 = packh2(A2, A3), pb23 = packh2(B2, B3);
#undef DOT8
            sA01 += u2h(pa01);  sA23 += u2h(pa23);
            sB01 += u2h(pb01);  sB23 += u2h(pb23);
            const int dst = (i << 3) + pb;
            *(uint2*)&uh[dst]           = make_uint2(pa01, pa23);
            *(uint2*)&uh[TILE_DW + dst] = make_uint2(pb01, pb23);
        };
#pragma unroll
        for (int k = 0; k < 4; ++k) stage(i0 + 256 * k);
        if (i0 < IC - 1024) stage(i0 + 1024);

#pragma unroll
        for (int o = 4; o <= 32; o <<= 1) {
            sA01 += hshfl_xor(sA01, o);  sA23 += hshfl_xor(sA23, o);
            sB01 += hshfl_xor(sB01, o);  sB23 += hshfl_xor(sB23, o);
        }
        if (lane < 4) {   // lane == q here; cp = 2q, 2q+1; padded stride 20
            const int c0 = lane << 1;
            r0p[c0 * 20 + wid]             = h2u(sA01);
            r0p[(c0 + 1) * 20 + wid]       = h2u(sA23);
            r0p[160 + c0 * 20 + wid]       = h2u(sB01);
            r0p[160 + (c0 + 1) * 20 + wid] = h2u(sB23);
        }
    }

    __syncthreads();  // B0: uhat + r0 partials ready

    // ---- Routing: balanced partition. Waves 0-5: 128 rows (2 passes);
    //      waves 6-7: 192 rows (3 passes). All passes full-wave. ----
    const int bt = wid >> 3;
    const int w8 = wid & 7;
    const bool w3p = (w8 >= 6);
    const int base0 = w3p ? (768 + (w8 - 6) * 192) : (w8 << 7);  // % 8 == 0
    const unsigned* uhT = uh + bt * TILE_DW;

    const int cp = lane & 7;               // m-pair this lane combines/stores
    const int i1 = base0 + lane, i2 = i1 + 64, i3 = base0 + 128 + lane;

    float L0 = 0.f, L1 = 0.f, L2 = w3p ? 0.f : -1e30f;

    for (int r = 0; r < 3; ++r) {
        if (r == 2 && w8 != 0) break;      // only w8==0 produces output

        // ---- combine -> s -> squash -> v (per-lane m-pair cp) ----
        float sx, sy;
        {
            v2f s2 = {0.f, 0.f};
            float inv;
            if (r == 0) {
                // r0p[bt][cp][16 of 20]: 4 x b128, two halves (VGPR guard)
                const unsigned* rp = &r0p[bt * 160 + cp * 20];
                h2 a2 = u2h(0u);
                {
                    const uint4 v0 = *(const uint4*)&rp[0];
                    const uint4 v1 = *(const uint4*)&rp[4];
                    a2 += u2h(v0.x) + u2h(v0.y) + u2h(v0.z) + u2h(v0.w);
                    a2 += u2h(v1.x) + u2h(v1.y) + u2h(v1.z) + u2h(v1.w);
                }
                {
                    const uint4 v2 = *(const uint4*)&rp[8];
                    const uint4 v3 = *(const uint4*)&rp[12];
                    a2 += u2h(v2.x) + u2h(v2.y) + u2h(v2.z) + u2h(v2.w);
                    a2 += u2h(v3.x) + u2h(v3.y) + u2h(v3.z) + u2h(v3.w);
                }
                s2.x = (float)a2.x; s2.y = (float)a2.y;
                inv = 1.0f / (float)IC;
            } else {
                const int base = ((r - 1) & 1) * 224;
                const unsigned* pp = &spart[base + bt * 96 + cp * 12];
                const unsigned* ee = &spart[base + 192 + bt * 16];
                float ses = 0.f;
#define CW(pw, fm, fs) { \
                const float fac = __uint_as_float(fm); \
                const v2f pv = h_v2(pw); \
                s2.x += pv.x * fac;  s2.y += pv.y * fac; \
                ses += __uint_as_float(fs) * fac; }
                {   // half 1: w = 0..3
                    const uint4 P0 = *(const uint4*)&pp[0];
                    const uint4 E0 = *(const uint4*)&ee[0];
                    const uint4 E1 = *(const uint4*)&ee[4];
                    CW(P0.x, E0.x, E0.y) CW(P0.y, E0.z, E0.w)
                    CW(P0.z, E1.x, E1.y) CW(P0.w, E1.z, E1.w)
                }
                {   // half 2: w = 4..7
                    const uint4 P1 = *(const uint4*)&pp[4];
                    const uint4 E2 = *(const uint4*)&ee[8];
                    const uint4 E3 = *(const uint4*)&ee[12];
                    CW(P1.x, E2.x, E2.y) CW(P1.y, E2.z, E2.w)
                    CW(P1.z, E3.x, E3.y) CW(P1.w, E3.z, E3.w)
                }
#undef CW
                inv = 1.0f / ses;
            }
            sx = s2.x * inv;  sy = s2.y * inv;
        }
        float p2 = sx * sx + sy * sy;
        p2 = qadd<0xB1>(p2);               // xor1 (quad_perm, VALU)
        p2 = qadd<0x4E>(p2);               // xor2
        p2 += __int_as_float(__builtin_amdgcn_ds_swizzle(__float_as_int(p2), 0x101F)); // xor4
        const float sc = p2 / ((1.0f + p2) * sqrtf(p2 + 1e-8f));
        const float vx = sx * sc, vy = sy * sc;

        if (r == 2) {
            if (lane < 8)
                *(float2*)&out[((size_t)(bb + bt) * OC + j) * 16 + (cp << 1)] =
                    make_float2(vx, vy);
            break;
        }

        // ---- broadcast v into position space: compile-time ds_swizzle ----
        const int pki = (int)packh2(vx, vy);
        unsigned vh[8];
        vh[0] = (unsigned)__builtin_amdgcn_ds_swizzle(pki, 0x001C);
        vh[1] = (unsigned)__builtin_amdgcn_ds_swizzle(pki, 0x003C);
        vh[2] = (unsigned)__builtin_amdgcn_ds_swizzle(pki, 0x005C);
        vh[3] = (unsigned)__builtin_amdgcn_ds_swizzle(pki, 0x007C);
        vh[4] = (unsigned)__builtin_amdgcn_ds_swizzle(pki, 0x101C);
        vh[5] = (unsigned)__builtin_amdgcn_ds_swizzle(pki, 0x103C);
        vh[6] = (unsigned)__builtin_amdgcn_ds_swizzle(pki, 0x105C);
        vh[7] = (unsigned)__builtin_amdgcn_ds_swizzle(pki, 0x107C);

        // ---- pass1: dp -> L (all passes full-wave) ----
#define DP8(Lk, ii) { \
        const uint4 da = *(const uint4*)&uhT[(ii) << 3]; \
        const uint4 db = *(const uint4*)&uhT[((ii) << 3) + 4]; \
        float d1 = fdot2f(da.x, vh[0], 0.f); d1 = fdot2f(da.y, vh[1], d1); \
        d1 = fdot2f(da.z, vh[2], d1); d1 = fdot2f(da.w, vh[3], d1); \
        float d2 = fdot2f(db.x, vh[4], 0.f); d2 = fdot2f(db.y, vh[5], d2); \
        d2 = fdot2f(db.z, vh[6], d2); d2 = fdot2f(db.w, vh[7], d2); \
        (Lk) += d1 + d2; }
        DP8(L0, i1)
        DP8(L1, i2)
        if (w3p) { DP8(L2, i3) }
#undef DP8

        // ---- wave max via DPP ladder (range guard for f16 partials) ----
        const float M = dpp_wave_max(fmaxf(L0, fmaxf(L1, L2)));

        // ---- pass2: ev = exp(L-M); se; s-partials via v_pk_fma_f16 ----
        h2 sa[8];
#pragma unroll
        for (int k = 0; k < 8; ++k) sa[k] = u2h(0u);
        float sel = 0.f;
#define ROW2(Lk, ii) { \
        const uint4 da = *(const uint4*)&uhT[(ii) << 3]; \
        const uint4 db = *(const uint4*)&uhT[((ii) << 3) + 4]; \
        const float ev = __expf((Lk) - M); \
        sel += ev; \
        const h2 eh = u2h(packh2(ev, ev)); \
        sa[0] += u2h(da.x) * eh;  sa[1] += u2h(da.y) * eh; \
        sa[2] += u2h(da.z) * eh;  sa[3] += u2h(da.w) * eh; \
        sa[4] += u2h(db.x) * eh;  sa[5] += u2h(db.y) * eh; \
        sa[6] += u2h(db.z) * eh;  sa[7] += u2h(db.w) * eh; }
        ROW2(L0, i1)
        ROW2(L1, i2)
        if (w3p) { ROW2(L2, i3) }
#undef ROW2
        const float se = dpp_wave_sum(sel);

        // ---- narrowing XOR tree; step1 selects on (lane5 ^ eB) => m-space ----
        h2 tt;
        {
            const int eB = (lane >> 2) & 1;
            const bool s5 = (((lane >> 5) & 1) ^ eB) != 0;
            const bool b4 = (lane & 16) != 0, b3 = (lane & 8) != 0;
            h2 tq[4];
#pragma unroll
            for (int q = 0; q < 4; ++q) {
                h2 snd = s5 ? sa[q] : sa[q + 4];
                tq[q] = (s5 ? sa[q + 4] : sa[q]) + hshfl_xor(snd, 32);
            }
            h2 uq[2];
#pragma unroll
            for (int q = 0; q < 2; ++q) {
                h2 snd = b4 ? tq[q] : tq[q + 2];
                uq[q] = (b4 ? tq[q + 2] : tq[q]) + hshfl_xor(snd, 16);
            }
            {
                h2 snd = b3 ? uq[0] : uq[1];
                tt = (b3 ? uq[1] : uq[0]) + hshfl_xor(snd, 8);
            }
            tt += u2h((unsigned)__builtin_amdgcn_ds_swizzle((int)h2u(tt), 0x101F)); // xor4
            tt = hqadd<0x4E>(tt);          // xor2 (quad_perm)
            tt = hqadd<0xB1>(tt);          // xor1
        }

        // ---- store partials: [bt][cp*12][w8] (padded) + (e^M, se)[bt][w8] ----
        const int po = (r & 1) * 224;
        if ((lane & 7) == 0)
            spart[po + bt * 96 + (lane >> 3) * 12 + w8] = h2u(tt);
        if (lane == 1)
            *(float2*)&spart[po + 192 + (bt * 8 + w8) * 2] = make_float2(__expf(M), se);
        __syncthreads();  // B(r+1)
    }
}

extern "C" void kernel_launch(void* const* d_in, const int* in_sizes, int n_in,
                              void* d_out, int out_size, void* d_ws, size_t ws_size,
                              hipStream_t stream) {
    const float* u = (const float*)d_in[0];
    const float* W = (const float*)d_in[1];
    float* out = (float*)d_out;
    unsigned* ws = (unsigned*)d_ws;

    const int do_u = (ws_size >= WS_NEED) ? 1 : 0;
    const int total = NWT + (do_u ? NUT : 0);
    convert_kernel<<<(total + 255) / 256, 256, 0, stream>>>(u, W, ws, do_u);

    const size_t shmem = (size_t)(2 * TILE_DW + 320 + 448) * 4;  // 76800 B
    if (do_u) {
        hipFuncSetAttribute((const void*)caps_route_kernel<true>,
                            hipFuncAttributeMaxDynamicSharedMemorySize, (int)shmem);
        caps_route_kernel<true><<<(NB / 2) * OC, 1024, shmem, stream>>>(u, ws, ws + NW_DW, out);
    } else {
        hipFuncSetAttribute((const void*)caps_route_kernel<false>,
                            hipFuncAttributeMaxDynamicSharedMemorySize, (int)shmem);
        caps_route_kernel<false><<<(NB / 2) * OC, 1024, shmem, stream>>>(u, ws, ws + NW_DW, out);
    }
}